// Round 5
// baseline (539.667 us; speedup 1.0000x reference)
//
#include <hip/hip_runtime.h>
#include <math.h>

#define H_HEADS 8
#define C_DIM   32
#define HC      256
#define F_IN    512
#define NEG_SLOPE 0.2f

typedef __attribute__((ext_vector_type(8))) short    bf16x8;
typedef __attribute__((ext_vector_type(4))) short    s16x4;
typedef __attribute__((ext_vector_type(4))) float    f32x4;
typedef __attribute__((ext_vector_type(2))) float    f32x2;
typedef __attribute__((ext_vector_type(8))) _Float16 h16x8;

__device__ __forceinline__ short f2bf(float f) {
    union { float f; unsigned u; } v; v.f = f;
    unsigned r = v.u + 0x7FFF + ((v.u >> 16) & 1);   // RNE
    return (short)(r >> 16);
}

// packed fp32->bf16 (RNE), 8 elems in 4 instructions
__device__ __forceinline__ bf16x8 cvt8(float4 a, float4 b) {
    union { bf16x8 v; unsigned u[4]; } r;
    asm("v_cvt_pk_bf16_f32 %0, %1, %2" : "=v"(r.u[0]) : "v"(a.x), "v"(a.y));
    asm("v_cvt_pk_bf16_f32 %0, %1, %2" : "=v"(r.u[1]) : "v"(a.z), "v"(a.w));
    asm("v_cvt_pk_bf16_f32 %0, %1, %2" : "=v"(r.u[2]) : "v"(b.x), "v"(b.y));
    asm("v_cvt_pk_bf16_f32 %0, %1, %2" : "=v"(r.u[3]) : "v"(b.z), "v"(b.w));
    return r.v;
}

__device__ __forceinline__ void gl2lds16(const short* g, short* l) {
    __builtin_amdgcn_global_load_lds(
        (const __attribute__((address_space(1))) void*)g,
        (__attribute__((address_space(3))) void*)l, 16, 0, 0);
}

// ---------------------------------------------------------------------------
// Fused prep: W1/W2 repack to MFMA B-frag order + x fp32->bf16 stream.
// ---------------------------------------------------------------------------
__global__ __launch_bounds__(256) void prep_kernel(const float* __restrict__ W1,
    const float* __restrict__ W2, const float* __restrict__ x,
    short* __restrict__ Wf1, short* __restrict__ Wf2, short* __restrict__ xbf,
    int nx)   // nx = N*F_IN
{
    const int NW1 = F_IN * HC;
    const int NW2 = HC * HC;
    int tid = blockIdx.x * 256 + threadIdx.x;
    if (tid < NW1) {
        int j  = tid & 7;
        int l  = (tid >> 3) & 63;
        int nb = (tid >> 9) & 15;
        int s  = tid >> 13;
        int k  = s * 32 + (l >> 4) * 8 + j;
        int n  = nb * 16 + (l & 15);
        Wf1[tid] = f2bf(W1[(size_t)k * HC + n]);
    } else if (tid < NW1 + NW2) {
        int t  = tid - NW1;
        int j  = t & 7;
        int l  = (t >> 3) & 63;
        int nb = (t >> 9) & 15;
        int s  = t >> 13;
        int k  = s * 32 + (l >> 4) * 8 + j;
        int n  = nb * 16 + (l & 15);
        Wf2[t] = f2bf(W2[(size_t)k * HC + n]);
    } else {
        size_t idx = (size_t)(tid - NW1 - NW2) * 8;
        if (idx < (size_t)nx) {
            float4 a = *(const float4*)(x + idx);
            float4 b = *(const float4*)(x + idx + 4);
            *(bf16x8*)(xbf + idx) = cvt8(a, b);
        }
    }
}

// ---------------------------------------------------------------------------
// MFMA GEMM + fused epilogue (BM=64, BK=32, 36 KB LDS, bf16 A).
// K-loop uses counted-vmcnt + raw s_barrier with DEPTH-2 A-prefetch:
// per-iter VMEM issue order = [stage(s+1) x4, A(s+2)]; at the top of iter s
// the queue is [A(s), stage(s) x4, A(s+1)] -> s_waitcnt vmcnt(1) drains the
// staging while A(s+1) stays in flight ACROSS the barrier (~2 phases of
// latency cover per A load). A-issue is clamped (always 1/iter) so the
// count is uniform; stage is guarded (last stage at iter nsteps-2).
// ---------------------------------------------------------------------------
__global__ __launch_bounds__(256) void gemm_mfma(const short* __restrict__ A16,
    const short* __restrict__ Bf, unsigned char* __restrict__ h8,
    const float* __restrict__ a_s, const float* __restrict__ a_d,
    float* __restrict__ alpha_s, float* __restrict__ alpha_d, int M, int K)
{
    __shared__ short Bs[2][8192];            // 2 x 16 KB K-step tiles
    __shared__ float Als[512], Ald[512];     // 64 rows x 8 heads

    const int tid  = threadIdx.x;
    const int w    = tid >> 6;
    const int lane = tid & 63;
    const int quad = lane >> 4;
    const int ml   = lane & 15;
    const int bm   = blockIdx.x * 64;

    const int rowA = bm + w * 16 + ml;
    const int rowL = rowA < M ? rowA : M - 1;
    const short* Arow = A16 + (size_t)rowL * K + quad * 8;

    f32x4 acc[16];
    #pragma unroll
    for (int nb = 0; nb < 16; ++nb) acc[nb] = (f32x4){0.f, 0.f, 0.f, 0.f};

    const int nsteps = K >> 5;

    {   // stage B step 0 (oldest in VMEM queue)
        const short* g = Bf + (size_t)w * 2048 + lane * 8;
        short* l = &Bs[0][w * 2048];
        #pragma unroll
        for (int c = 0; c < 4; ++c) gl2lds16(g + c * 512, l + c * 512);
    }
    __builtin_amdgcn_sched_barrier(0);

    bf16x8 pb[2];
    pb[0] = *(const bf16x8*)(Arow);          // A(0)
    pb[1] = *(const bf16x8*)(Arow + 32);     // A(1)  (K >= 64 always)
    __builtin_amdgcn_sched_barrier(0);

    for (int s = 0; s < nsteps; ++s) {
        // queue: [A(s), stage(s) x4, A(s+1)] -> drain stage+A(s), keep A(s+1)
        asm volatile("s_waitcnt vmcnt(1)" ::: "memory");
        __builtin_amdgcn_s_barrier();

        if (s + 1 < nsteps) {   // stage B step s+1 (issued first -> oldest)
            const short* g = Bf + (size_t)(s + 1) * 8192 + w * 2048 + lane * 8;
            short* l = &Bs[(s + 1) & 1][w * 2048];
            #pragma unroll
            for (int c = 0; c < 4; ++c) gl2lds16(g + c * 512, l + c * 512);
        }
        __builtin_amdgcn_sched_barrier(0);

        bf16x8 af = pb[s & 1];
        {   // clamped A-prefetch: always exactly 1 VMEM load per iter
            int ks2 = s + 2 < nsteps ? s + 2 : nsteps - 1;
            pb[s & 1] = *(const bf16x8*)(Arow + ks2 * 32);
        }
        __builtin_amdgcn_sched_barrier(0);

        const short* bsrc = &Bs[s & 1][lane * 8];
        #pragma unroll
        for (int nb = 0; nb < 16; ++nb) {
            bf16x8 bfr = *(const bf16x8*)(bsrc + nb * 512);
            acc[nb] = __builtin_amdgcn_mfma_f32_16x16x32_bf16(af, bfr, acc[nb], 0, 0, 0);
        }
    }

    // ---- epilogue: fp8 store + fused per-head alpha dots ----
    float as_v[16], ad_v[16];
    #pragma unroll
    for (int nb = 0; nb < 16; ++nb) {
        as_v[nb] = a_s[nb * 16 + ml];
        ad_v[nb] = a_d[nb * 16 + ml];
    }

    #pragma unroll
    for (int r = 0; r < 4; ++r) {
        const int rl  = w * 16 + quad * 4 + r;
        const int row = bm + rl;

        if (row < M) {
            unsigned char* hrow = h8 + (size_t)row * HC;
            #pragma unroll
            for (int i = 0; i < 8; ++i) {
                int pk = __builtin_amdgcn_cvt_pk_fp8_f32(acc[2 * i][r], acc[2 * i + 1][r], 0, false);
                hrow[(2 * i) * 16 + ml]     = (unsigned char)(pk & 0xFF);
                hrow[(2 * i + 1) * 16 + ml] = (unsigned char)((pk >> 8) & 0xFF);
            }
        }

        float hs[8], hd[8];
        #pragma unroll
        for (int q = 0; q < 8; ++q) {
            hs[q] = acc[2 * q][r] * as_v[2 * q] + acc[2 * q + 1][r] * as_v[2 * q + 1];
            hd[q] = acc[2 * q][r] * ad_v[2 * q] + acc[2 * q + 1][r] * ad_v[2 * q + 1];
        }
        #pragma unroll
        for (int off = 1; off < 16; off <<= 1) {
            #pragma unroll
            for (int q = 0; q < 8; ++q) {
                hs[q] += __shfl_xor(hs[q], off);
                hd[q] += __shfl_xor(hd[q], off);
            }
        }
        if (ml == 0) {
            #pragma unroll
            for (int q = 0; q < 8; ++q) {
                Als[rl * 8 + q] = hs[q];
                Ald[rl * 8 + q] = hd[q];
            }
        }
    }
    __syncthreads();
    #pragma unroll
    for (int k = 0; k < 2; ++k) {
        int idx = tid + k * 256;
        int rl = idx >> 3, q = idx & 7;
        int row = bm + rl;
        if (row < M) {
            alpha_s[(size_t)row * H_HEADS + q] = Als[idx];
            alpha_d[(size_t)row * H_HEADS + q] = Ald[idx];
        }
    }
}

// ---------------------------------------------------------------------------
// Per-edge softmax weights (fp16): w[p,h] = exp(leaky(alpha_s[src]+alpha_d[dst]))
// ---------------------------------------------------------------------------
__global__ __launch_bounds__(256) void wcalc_kernel(const int2* __restrict__ es,
    const float* __restrict__ alpha_s, const float* __restrict__ alpha_d,
    _Float16* __restrict__ wq, int P)
{
    int p = blockIdx.x * 256 + threadIdx.x;
    if (p >= P) return;
    int2 sd = es[p];
    const float4* as = (const float4*)(alpha_s + (size_t)sd.x * H_HEADS);
    const float4* ad = (const float4*)(alpha_d + (size_t)sd.y * H_HEADS);
    float4 s0 = as[0], s1 = as[1], d0 = ad[0], d1 = ad[1];
    float e[8] = {s0.x + d0.x, s0.y + d0.y, s0.z + d0.z, s0.w + d0.w,
                  s1.x + d1.x, s1.y + d1.y, s1.z + d1.z, s1.w + d1.w};
    h16x8 o;
    #pragma unroll
    for (int h = 0; h < 8; ++h) {
        float v = e[h] > 0.f ? e[h] : NEG_SLOPE * e[h];
        o[h] = (_Float16)__expf(v);
    }
    *(h16x8*)(wq + (size_t)p * H_HEADS) = o;
}

// ---------------------------------------------------------------------------
// CSR build
// ---------------------------------------------------------------------------
__global__ void zero_int(int* __restrict__ p, int n)
{
    int i = blockIdx.x * 256 + threadIdx.x;
    if (i < n) p[i] = 0;
}

__global__ void hist_kernel(const int* __restrict__ ei, int E, int N,
                            int* __restrict__ cnt)
{
    int e = blockIdx.x * 256 + threadIdx.x;
    if (e < E) atomicAdd(&cnt[ei[E + e]], 1);
    else if (e < E + N) atomicAdd(&cnt[e - E], 1);
}

__global__ __launch_bounds__(256) void scan_sum(const int* __restrict__ cnt, int n,
                                                int* __restrict__ chunk_sum)
{
    __shared__ int lds[256];
    int b = blockIdx.x, t = threadIdx.x;
    int base = b * 1024 + t * 4;
    int s = 0;
    #pragma unroll
    for (int j = 0; j < 4; ++j) { int i = base + j; if (i < n) s += cnt[i]; }
    lds[t] = s; __syncthreads();
    for (int off = 128; off > 0; off >>= 1) {
        if (t < off) lds[t] += lds[t + off];
        __syncthreads();
    }
    if (t == 0) chunk_sum[b] = lds[0];
}

// scan_local with inlined chunk-offset computation (was scan_top):
// each wave reduces the <=64 chunk sums itself. Last block writes row_ptr[n].
__global__ __launch_bounds__(256) void scan_local(const int* __restrict__ cnt, int n,
    const int* __restrict__ chunk_sum, int nch, int* __restrict__ row_ptr)
{
    __shared__ int lds[256];
    int b = blockIdx.x, t = threadIdx.x;
    int lane = t & 63;

    int cs  = (lane < nch) ? chunk_sum[lane] : 0;
    int pre = (lane < b)   ? cs : 0;
    int tot = cs;
    #pragma unroll
    for (int off = 32; off > 0; off >>= 1) {
        pre += __shfl_xor(pre, off);
        tot += __shfl_xor(tot, off);
    }
    // pre = sum of chunk_sum[0..b-1], tot = total (same in all lanes)

    int base = b * 1024 + t * 4;
    int v[4]; int s = 0;
    #pragma unroll
    for (int j = 0; j < 4; ++j) { int i = base + j; v[j] = (i < n) ? cnt[i] : 0; s += v[j]; }
    lds[t] = s; __syncthreads();
    for (int off = 1; off < 256; off <<= 1) {
        int u = (t >= off) ? lds[t - off] : 0;
        __syncthreads();
        lds[t] += u;
        __syncthreads();
    }
    int run = lds[t] - s + pre;
    #pragma unroll
    for (int j = 0; j < 4; ++j) {
        int i = base + j;
        if (i < n) row_ptr[i] = run;
        run += v[j];
    }
    if (b == gridDim.x - 1 && t == 0) row_ptr[n] = tot;
}

// Reverse-fill scatter: consumes cnt (atomicSub), no separate fill array.
__global__ void scatter_kernel(const int* __restrict__ ei, int E, int N,
    const int* __restrict__ row_ptr, int* __restrict__ cnt, int2* __restrict__ es)
{
    int e = blockIdx.x * 256 + threadIdx.x;
    int src, dst;
    if (e < E)          { src = ei[e]; dst = ei[E + e]; }
    else if (e < E + N) { src = dst = e - E; }
    else return;
    int pos = row_ptr[dst] + atomicSub(&cnt[dst], 1) - 1;
    es[pos] = make_int2(src, dst);
}

// ---------------------------------------------------------------------------
// Layer-1 aggregation: one wave per dst node, lane owns 4 channels (fp8 dword
// gather), x8 unrolled edge loop. z written bf16 (layer-2 GEMM A input).
// ---------------------------------------------------------------------------
__global__ __launch_bounds__(256) void agg1_kernel(const unsigned* __restrict__ h8,
    const _Float16* __restrict__ wq, const int* __restrict__ row_ptr,
    const int2* __restrict__ es, const float* __restrict__ bias,
    short* __restrict__ z_bf, int N)
{
    const int l = threadIdx.x & 63;
    const int i = blockIdx.x * 4 + (threadIdx.x >> 6);
    if (i >= N) return;
    const int hh = l >> 3;
    const int beg = row_ptr[i], end = row_ptr[i + 1];
    f32x4 acc = {0.f, 0.f, 0.f, 0.f};
    float dsum = 0.f;
    int p = beg;
    for (; p + 7 < end; p += 8) {
        int s[8]; float w[8]; unsigned hv[8];
        #pragma unroll
        for (int u = 0; u < 8; ++u) s[u] = es[p + u].x;
        #pragma unroll
        for (int u = 0; u < 8; ++u) w[u] = (float)wq[(size_t)(p + u) * 8 + hh];
        #pragma unroll
        for (int u = 0; u < 8; ++u) hv[u] = h8[(size_t)s[u] * 64 + l];
        #pragma unroll
        for (int u = 0; u < 8; ++u) {
            f32x2 lo = __builtin_amdgcn_cvt_pk_f32_fp8(hv[u], false);
            f32x2 hi = __builtin_amdgcn_cvt_pk_f32_fp8(hv[u], true);
            acc[0] = fmaf(w[u], lo[0], acc[0]);
            acc[1] = fmaf(w[u], lo[1], acc[1]);
            acc[2] = fmaf(w[u], hi[0], acc[2]);
            acc[3] = fmaf(w[u], hi[1], acc[3]);
            dsum += w[u];
        }
    }
    for (; p < end; ++p) {
        int s0 = es[p].x;
        float w0 = (float)wq[(size_t)p * 8 + hh];
        unsigned hv = h8[(size_t)s0 * 64 + l];
        f32x2 lo = __builtin_amdgcn_cvt_pk_f32_fp8(hv, false);
        f32x2 hi = __builtin_amdgcn_cvt_pk_f32_fp8(hv, true);
        acc[0] = fmaf(w0, lo[0], acc[0]);
        acc[1] = fmaf(w0, lo[1], acc[1]);
        acc[2] = fmaf(w0, hi[0], acc[2]);
        acc[3] = fmaf(w0, hi[1], acc[3]);
        dsum += w0;
    }
    float inv = 1.f / (dsum + 1e-16f);
    s16x4 pk;
    #pragma unroll
    for (int j = 0; j < 4; ++j) {
        float z = acc[j] * inv + bias[4 * l + j];
        pk[j] = f2bf(z > 0.f ? z : 0.f);
    }
    *(s16x4*)(z_bf + (size_t)i * HC + 4 * l) = pk;
}

// ---------------------------------------------------------------------------
// Layer-2 aggregation fused with head-mean + b2 + Wp dot + sigmoid.
// ---------------------------------------------------------------------------
__global__ __launch_bounds__(256) void agg2_kernel(const unsigned* __restrict__ h8,
    const _Float16* __restrict__ wq, const int* __restrict__ row_ptr,
    const int2* __restrict__ es, const float* __restrict__ b2,
    const float* __restrict__ Wp, const float* __restrict__ bp,
    float* __restrict__ out, int N)
{
    const int l = threadIdx.x & 63;
    const int i = blockIdx.x * 4 + (threadIdx.x >> 6);
    if (i >= N) return;
    const int hh = l >> 3;
    const int beg = row_ptr[i], end = row_ptr[i + 1];
    f32x4 acc = {0.f, 0.f, 0.f, 0.f};
    float dsum = 0.f;
    int p = beg;
    for (; p + 7 < end; p += 8) {
        int s[8]; float w[8]; unsigned hv[8];
        #pragma unroll
        for (int u = 0; u < 8; ++u) s[u] = es[p + u].x;
        #pragma unroll
        for (int u = 0; u < 8; ++u) w[u] = (float)wq[(size_t)(p + u) * 8 + hh];
        #pragma unroll
        for (int u = 0; u < 8; ++u) hv[u] = h8[(size_t)s[u] * 64 + l];
        #pragma unroll
        for (int u = 0; u < 8; ++u) {
            f32x2 lo = __builtin_amdgcn_cvt_pk_f32_fp8(hv[u], false);
            f32x2 hi = __builtin_amdgcn_cvt_pk_f32_fp8(hv[u], true);
            acc[0] = fmaf(w[u], lo[0], acc[0]);
            acc[1] = fmaf(w[u], lo[1], acc[1]);
            acc[2] = fmaf(w[u], hi[0], acc[2]);
            acc[3] = fmaf(w[u], hi[1], acc[3]);
            dsum += w[u];
        }
    }
    for (; p < end; ++p) {
        int s0 = es[p].x;
        float w0 = (float)wq[(size_t)p * 8 + hh];
        unsigned hv = h8[(size_t)s0 * 64 + l];
        f32x2 lo = __builtin_amdgcn_cvt_pk_f32_fp8(hv, false);
        f32x2 hi = __builtin_amdgcn_cvt_pk_f32_fp8(hv, true);
        acc[0] = fmaf(w0, lo[0], acc[0]);
        acc[1] = fmaf(w0, lo[1], acc[1]);
        acc[2] = fmaf(w0, hi[0], acc[2]);
        acc[3] = fmaf(w0, hi[1], acc[3]);
        dsum += w0;
    }
    float inv = 1.f / (dsum + 1e-16f);
    int cc = (4 * l) & 31;
    float partial = 0.f;
    #pragma unroll
    for (int j = 0; j < 4; ++j) partial = fmaf(acc[j] * inv, Wp[cc + j], partial);
    if (l < 8) {
        #pragma unroll
        for (int j = 0; j < 4; ++j) partial = fmaf(8.f * b2[4 * l + j], Wp[4 * l + j], partial);
    }
    #pragma unroll
    for (int off = 32; off > 0; off >>= 1) partial += __shfl_xor(partial, off);
    if (l == 0) out[i] = 1.f / (1.f + __expf(-(0.125f * partial + bp[0])));
}

// ---------------------------------------------------------------------------
extern "C" void kernel_launch(void* const* d_in, const int* in_sizes, int n_in,
                              void* d_out, int out_size, void* d_ws, size_t ws_size,
                              hipStream_t stream)
{
    const int*   ei  = (const int*)d_in[0];
    const float* x   = (const float*)d_in[1];
    const float* W1  = (const float*)d_in[2];
    const float* as1 = (const float*)d_in[3];
    const float* ad1 = (const float*)d_in[4];
    const float* b1  = (const float*)d_in[5];
    const float* W2  = (const float*)d_in[6];
    const float* as2 = (const float*)d_in[7];
    const float* ad2 = (const float*)d_in[8];
    const float* b2  = (const float*)d_in[9];
    const float* Wp  = (const float*)d_in[10];
    const float* bp  = (const float*)d_in[11];
    float* out = (float*)d_out;

    const int E = in_sizes[0] / 2;
    const int N = in_sizes[1] / F_IN;
    const int ET = E + N;

    // workspace layout (16B-aligned sections)
    float*         asb = (float*)d_ws;                           // N*8 f32
    float*         adb = asb + (size_t)N * H_HEADS;              // N*8 f32
    unsigned char* h8  = (unsigned char*)(adb + (size_t)N * H_HEADS); // N*256 fp8
    short*         xz  = (short*)(h8 + (size_t)N * HC);          // N*512 bf16 region
    short*         xbf = xz;                                     // x bf16 (dead after gemm1)
    short*         z1b = xz;                                     // z1 bf16 (written by agg1)
    short*         Wf1 = xz + (size_t)N * F_IN;                  // 512*256 bf16
    short*         Wf2 = Wf1 + (size_t)F_IN * HC;                // 256*256 bf16
    _Float16*      wq  = (_Float16*)(Wf2 + (size_t)HC * HC);     // (E+N)*8 fp16
    int2*          es  = (int2*)(wq + (size_t)ET * H_HEADS);     // (E+N) int2
    int* cnt       = (int*)(es + ET);                            // N
    int* row_ptr   = cnt + N;                                    // N+1
    int* chunk_sum = row_ptr + N + 1;                            // 64

    const int NCH = (N + 1023) / 1024;
    const int MB  = (N + 63) / 64;
    const int NB4 = (N + 3) / 4;
    const int NPREP = (F_IN * HC + HC * HC + (N * F_IN) / 8 + 255) / 256;

    // ---- CSR build ----
    zero_int<<<(N + 255) / 256, 256, 0, stream>>>(cnt, N);
    hist_kernel<<<(ET + 255) / 256, 256, 0, stream>>>(ei, E, N, cnt);
    scan_sum<<<NCH, 256, 0, stream>>>(cnt, N, chunk_sum);
    scan_local<<<NCH, 256, 0, stream>>>(cnt, N, chunk_sum, NCH, row_ptr);
    scatter_kernel<<<(ET + 255) / 256, 256, 0, stream>>>(ei, E, N, row_ptr, cnt, es);

    // ---- W repack + x->bf16 (x_bf left hot in L3 for gemm1) ----
    prep_kernel<<<NPREP, 256, 0, stream>>>(W1, W2, x, Wf1, Wf2, xbf, N * F_IN);

    // ---- Layer 1 ----
    gemm_mfma<<<MB, 256, 0, stream>>>(xbf, Wf1, h8, as1, ad1, asb, adb, N, F_IN);
    wcalc_kernel<<<(ET + 255) / 256, 256, 0, stream>>>(es, asb, adb, wq, ET);
    agg1_kernel<<<NB4, 256, 0, stream>>>((const unsigned*)h8, wq, row_ptr, es, b1, z1b, N);

    // ---- Layer 2 ----
    gemm_mfma<<<MB, 256, 0, stream>>>(z1b, Wf2, h8, as2, ad2, asb, adb, N, HC);
    wcalc_kernel<<<(ET + 255) / 256, 256, 0, stream>>>(es, asb, adb, wq, ET);
    agg2_kernel<<<NB4, 256, 0, stream>>>((const unsigned*)h8, wq, row_ptr, es, b2, Wp, bp, out, N);
}

// Round 6
// 419.925 us; speedup vs baseline: 1.2852x; 1.2852x over previous
//
#include <hip/hip_runtime.h>
#include <math.h>

#define H_HEADS 8
#define C_DIM   32
#define HC      256
#define F_IN    512
#define NEG_SLOPE 0.2f

typedef __attribute__((ext_vector_type(8))) short    bf16x8;
typedef __attribute__((ext_vector_type(4))) short    s16x4;
typedef __attribute__((ext_vector_type(4))) float    f32x4;
typedef __attribute__((ext_vector_type(2))) float    f32x2;
typedef __attribute__((ext_vector_type(8))) _Float16 h16x8;

__device__ __forceinline__ short f2bf(float f) {
    union { float f; unsigned u; } v; v.f = f;
    unsigned r = v.u + 0x7FFF + ((v.u >> 16) & 1);   // RNE
    return (short)(r >> 16);
}

__device__ __forceinline__ void gl2lds16(const short* g, short* l) {
    __builtin_amdgcn_global_load_lds(
        (const __attribute__((address_space(1))) void*)g,
        (__attribute__((address_space(3))) void*)l, 16, 0, 0);
}

// ---------------------------------------------------------------------------
// Repack W [K,256] fp32 -> MFMA B-frag-ordered bf16 (16 KB per K-step of 32).
// ---------------------------------------------------------------------------
__global__ void wfrag_kernel(const float* __restrict__ W, short* __restrict__ Wf, int K)
{
    int tid = blockIdx.x * 256 + threadIdx.x;
    if (tid >= K * HC) return;
    int j  = tid & 7;
    int l  = (tid >> 3) & 63;
    int nb = (tid >> 9) & 15;
    int s  = tid >> 13;
    int k  = s * 32 + (l >> 4) * 8 + j;
    int n  = nb * 16 + (l & 15);
    Wf[tid] = f2bf(W[(size_t)k * HC + n]);
}

// ---------------------------------------------------------------------------
// MFMA GEMM + fused epilogue — EXACT r0 structure (67 us verified; every
// manual schedule variant tried in r1-r5 regressed).
// ---------------------------------------------------------------------------
template<bool ABF16>
__global__ __launch_bounds__(256) void gemm_mfma(const void* __restrict__ Aptr,
    const short* __restrict__ Bf, unsigned char* __restrict__ h8,
    const float* __restrict__ a_s, const float* __restrict__ a_d,
    float* __restrict__ alpha_s, float* __restrict__ alpha_d, int M, int K)
{
    __shared__ short Bs[2][8192];            // 2 x 16 KB K-step tiles
    __shared__ float Als[512], Ald[512];     // 64 rows x 8 heads

    const int tid  = threadIdx.x;
    const int w    = tid >> 6;
    const int lane = tid & 63;
    const int quad = lane >> 4;
    const int ml   = lane & 15;
    const int bm   = blockIdx.x * 64;

    const int rowA = bm + w * 16 + ml;
    const int rowL = rowA < M ? rowA : M - 1;

    f32x4 acc[16];
    #pragma unroll
    for (int nb = 0; nb < 16; ++nb) acc[nb] = (f32x4){0.f, 0.f, 0.f, 0.f};

    const float* A32 = (const float*)Aptr;
    const short* A16 = (const short*)Aptr;
    const int nsteps = K >> 5;

    {   // stage B step 0
        const short* g = Bf + (size_t)w * 2048 + lane * 8;
        short* l = &Bs[0][w * 2048];
        #pragma unroll
        for (int c = 0; c < 4; ++c) gl2lds16(g + c * 512, l + c * 512);
    }

    float4 p0, p1;
    bf16x8 pb;
    if (ABF16) {
        pb = *(const bf16x8*)(A16 + (size_t)rowL * K + quad * 8);
    } else {
        const float* ap = A32 + (size_t)rowL * K + quad * 8;
        p0 = *(const float4*)(ap);
        p1 = *(const float4*)(ap + 4);
    }

    for (int s = 0; s < nsteps; ++s) {
        __syncthreads();

        if (s + 1 < nsteps) {
            const short* g = Bf + (size_t)(s + 1) * 8192 + w * 2048 + lane * 8;
            short* l = &Bs[(s + 1) & 1][w * 2048];
            #pragma unroll
            for (int c = 0; c < 4; ++c) gl2lds16(g + c * 512, l + c * 512);
        }

        bf16x8 af;
        if (ABF16) {
            af = pb;
            if (s + 1 < nsteps)
                pb = *(const bf16x8*)(A16 + (size_t)rowL * K + (s + 1) * 32 + quad * 8);
        } else {
            af[0] = f2bf(p0.x); af[1] = f2bf(p0.y); af[2] = f2bf(p0.z); af[3] = f2bf(p0.w);
            af[4] = f2bf(p1.x); af[5] = f2bf(p1.y); af[6] = f2bf(p1.z); af[7] = f2bf(p1.w);
            if (s + 1 < nsteps) {
                const float* ap = A32 + (size_t)rowL * K + (s + 1) * 32 + quad * 8;
                p0 = *(const float4*)(ap);
                p1 = *(const float4*)(ap + 4);
            }
        }

        const short* bsrc = &Bs[s & 1][lane * 8];
        #pragma unroll
        for (int nb = 0; nb < 16; ++nb) {
            bf16x8 bfr = *(const bf16x8*)(bsrc + nb * 512);
            acc[nb] = __builtin_amdgcn_mfma_f32_16x16x32_bf16(af, bfr, acc[nb], 0, 0, 0);
        }
    }

    // ---- epilogue: fp8 store + fused per-head alpha dots ----
    float as_v[16], ad_v[16];
    #pragma unroll
    for (int nb = 0; nb < 16; ++nb) {
        as_v[nb] = a_s[nb * 16 + ml];
        ad_v[nb] = a_d[nb * 16 + ml];
    }

    #pragma unroll
    for (int r = 0; r < 4; ++r) {
        const int rl  = w * 16 + quad * 4 + r;
        const int row = bm + rl;

        if (row < M) {
            unsigned char* hrow = h8 + (size_t)row * HC;
            #pragma unroll
            for (int i = 0; i < 8; ++i) {
                int pk = __builtin_amdgcn_cvt_pk_fp8_f32(acc[2 * i][r], acc[2 * i + 1][r], 0, false);
                hrow[(2 * i) * 16 + ml]     = (unsigned char)(pk & 0xFF);
                hrow[(2 * i + 1) * 16 + ml] = (unsigned char)((pk >> 8) & 0xFF);
            }
        }

        float hs[8], hd[8];
        #pragma unroll
        for (int q = 0; q < 8; ++q) {
            hs[q] = acc[2 * q][r] * as_v[2 * q] + acc[2 * q + 1][r] * as_v[2 * q + 1];
            hd[q] = acc[2 * q][r] * ad_v[2 * q] + acc[2 * q + 1][r] * ad_v[2 * q + 1];
        }
        #pragma unroll
        for (int off = 1; off < 16; off <<= 1) {
            #pragma unroll
            for (int q = 0; q < 8; ++q) {
                hs[q] += __shfl_xor(hs[q], off);
                hd[q] += __shfl_xor(hd[q], off);
            }
        }
        if (ml == 0) {
            #pragma unroll
            for (int q = 0; q < 8; ++q) {
                Als[rl * 8 + q] = hs[q];
                Ald[rl * 8 + q] = hd[q];
            }
        }
    }
    __syncthreads();
    #pragma unroll
    for (int k = 0; k < 2; ++k) {
        int idx = tid + k * 256;
        int rl = idx >> 3, q = idx & 7;
        int row = bm + rl;
        if (row < M) {
            alpha_s[(size_t)row * H_HEADS + q] = Als[idx];
            alpha_d[(size_t)row * H_HEADS + q] = Ald[idx];
        }
    }
}

// ---------------------------------------------------------------------------
// Per-edge softmax weights (fp16): w[p,h] = exp(leaky(alpha_s[src]+alpha_d[dst]))
// ---------------------------------------------------------------------------
__global__ __launch_bounds__(256) void wcalc_kernel(const int2* __restrict__ es,
    const float* __restrict__ alpha_s, const float* __restrict__ alpha_d,
    _Float16* __restrict__ wq, int P)
{
    int p = blockIdx.x * 256 + threadIdx.x;
    if (p >= P) return;
    int2 sd = es[p];
    const float4* as = (const float4*)(alpha_s + (size_t)sd.x * H_HEADS);
    const float4* ad = (const float4*)(alpha_d + (size_t)sd.y * H_HEADS);
    float4 s0 = as[0], s1 = as[1], d0 = ad[0], d1 = ad[1];
    float e[8] = {s0.x + d0.x, s0.y + d0.y, s0.z + d0.z, s0.w + d0.w,
                  s1.x + d1.x, s1.y + d1.y, s1.z + d1.z, s1.w + d1.w};
    h16x8 o;
    #pragma unroll
    for (int h = 0; h < 8; ++h) {
        float v = e[h] > 0.f ? e[h] : NEG_SLOPE * e[h];
        o[h] = (_Float16)__expf(v);
    }
    *(h16x8*)(wq + (size_t)p * H_HEADS) = o;
}

// ---------------------------------------------------------------------------
// CSR build
// ---------------------------------------------------------------------------
__global__ void zero_int(int* __restrict__ p, int n)
{
    int i = blockIdx.x * 256 + threadIdx.x;
    if (i < n) p[i] = 0;
}

__global__ void hist_kernel(const int* __restrict__ ei, int E, int N,
                            int* __restrict__ cnt)
{
    int e = blockIdx.x * 256 + threadIdx.x;
    if (e < E) atomicAdd(&cnt[ei[E + e]], 1);
    else if (e < E + N) atomicAdd(&cnt[e - E], 1);
}

__global__ __launch_bounds__(256) void scan_sum(const int* __restrict__ cnt, int n,
                                                int* __restrict__ chunk_sum)
{
    __shared__ int lds[256];
    int b = blockIdx.x, t = threadIdx.x;
    int base = b * 1024 + t * 4;
    int s = 0;
    #pragma unroll
    for (int j = 0; j < 4; ++j) { int i = base + j; if (i < n) s += cnt[i]; }
    lds[t] = s; __syncthreads();
    for (int off = 128; off > 0; off >>= 1) {
        if (t < off) lds[t] += lds[t + off];
        __syncthreads();
    }
    if (t == 0) chunk_sum[b] = lds[0];
}

// scan_local with inlined chunk-offset reduce (each wave reduces <=64 sums).
__global__ __launch_bounds__(256) void scan_local(const int* __restrict__ cnt, int n,
    const int* __restrict__ chunk_sum, int nch, int* __restrict__ row_ptr)
{
    __shared__ int lds[256];
    int b = blockIdx.x, t = threadIdx.x;
    int lane = t & 63;

    int cs  = (lane < nch) ? chunk_sum[lane] : 0;
    int pre = (lane < b)   ? cs : 0;
    int tot = cs;
    #pragma unroll
    for (int off = 32; off > 0; off >>= 1) {
        pre += __shfl_xor(pre, off);
        tot += __shfl_xor(tot, off);
    }

    int base = b * 1024 + t * 4;
    int v[4]; int s = 0;
    #pragma unroll
    for (int j = 0; j < 4; ++j) { int i = base + j; v[j] = (i < n) ? cnt[i] : 0; s += v[j]; }
    lds[t] = s; __syncthreads();
    for (int off = 1; off < 256; off <<= 1) {
        int u = (t >= off) ? lds[t - off] : 0;
        __syncthreads();
        lds[t] += u;
        __syncthreads();
    }
    int run = lds[t] - s + pre;
    #pragma unroll
    for (int j = 0; j < 4; ++j) {
        int i = base + j;
        if (i < n) row_ptr[i] = run;
        run += v[j];
    }
    if (b == gridDim.x - 1 && t == 0) row_ptr[n] = tot;
}

// Reverse-fill scatter: consumes cnt (atomicSub), no separate fill array.
__global__ void scatter_kernel(const int* __restrict__ ei, int E, int N,
    const int* __restrict__ row_ptr, int* __restrict__ cnt, int2* __restrict__ es)
{
    int e = blockIdx.x * 256 + threadIdx.x;
    int src, dst;
    if (e < E)          { src = ei[e]; dst = ei[E + e]; }
    else if (e < E + N) { src = dst = e - E; }
    else return;
    int pos = row_ptr[dst] + atomicSub(&cnt[dst], 1) - 1;
    es[pos] = make_int2(src, dst);
}

// ---------------------------------------------------------------------------
// Aggregation, 4-edges-per-wave layout:
//   lane l: edge slot eo = l>>4 (4 concurrent edges), channel quad c = l&15
//   gather = one dwordx4 (16 fp8 channels) per lane per edge-quad
//   -> 6 VMEM per 8 edges per lane (was 24 with the dword layout).
// End of loop: acc/dsum summed across the 4 slots via 2 shfl_xor levels.
// ---------------------------------------------------------------------------
#define ACC4(word, wgt, base_) do { \
    f32x2 lo_ = __builtin_amdgcn_cvt_pk_f32_fp8((word), false); \
    f32x2 hi_ = __builtin_amdgcn_cvt_pk_f32_fp8((word), true);  \
    acc[(base_) + 0] = fmaf((wgt), lo_[0], acc[(base_) + 0]); \
    acc[(base_) + 1] = fmaf((wgt), lo_[1], acc[(base_) + 1]); \
    acc[(base_) + 2] = fmaf((wgt), hi_[0], acc[(base_) + 2]); \
    acc[(base_) + 3] = fmaf((wgt), hi_[1], acc[(base_) + 3]); \
} while (0)

__global__ __launch_bounds__(256) void agg1_kernel(const unsigned char* __restrict__ h8,
    const _Float16* __restrict__ wq, const int* __restrict__ row_ptr,
    const int2* __restrict__ es, const float* __restrict__ bias,
    short* __restrict__ z_bf, int N)
{
    const int l  = threadIdx.x & 63;
    const int i  = blockIdx.x * 4 + (threadIdx.x >> 6);
    if (i >= N) return;
    const int c  = l & 15;      // channels 16c..16c+15
    const int eo = l >> 4;      // edge slot
    const int hh = c >> 1;      // head of this lane's channels
    const int beg = row_ptr[i], end = row_ptr[i + 1];

    float acc[16];
    #pragma unroll
    for (int j = 0; j < 16; ++j) acc[j] = 0.f;
    float dsum = 0.f;

    int p = beg;
    for (; p + 7 < end; p += 8) {
        int p0 = p + eo, p1 = p + 4 + eo;
        int s0 = es[p0].x, s1 = es[p1].x;
        float w0 = (float)wq[(size_t)p0 * 8 + hh];
        float w1 = (float)wq[(size_t)p1 * 8 + hh];
        uint4 h0 = *(const uint4*)(h8 + (size_t)s0 * 256 + c * 16);
        uint4 h1 = *(const uint4*)(h8 + (size_t)s1 * 256 + c * 16);
        ACC4(h0.x, w0, 0); ACC4(h0.y, w0, 4); ACC4(h0.z, w0, 8); ACC4(h0.w, w0, 12);
        ACC4(h1.x, w1, 0); ACC4(h1.y, w1, 4); ACC4(h1.z, w1, 8); ACC4(h1.w, w1, 12);
        dsum += w0 + w1;
    }
    for (; p < end; p += 4) {
        int pe = p + eo;
        int pc = pe < end ? pe : end - 1;
        int s0 = es[pc].x;
        float w0 = pe < end ? (float)wq[(size_t)pc * 8 + hh] : 0.f;
        uint4 h0 = *(const uint4*)(h8 + (size_t)s0 * 256 + c * 16);
        ACC4(h0.x, w0, 0); ACC4(h0.y, w0, 4); ACC4(h0.z, w0, 8); ACC4(h0.w, w0, 12);
        dsum += w0;
    }

    #pragma unroll
    for (int j = 0; j < 16; ++j) {
        acc[j] += __shfl_xor(acc[j], 32);
        acc[j] += __shfl_xor(acc[j], 16);
    }
    dsum += __shfl_xor(dsum, 32);
    dsum += __shfl_xor(dsum, 16);

    float inv = 1.f / (dsum + 1e-16f);
    if (eo == 0) {
        union { short s[16]; bf16x8 v[2]; } zz;
        #pragma unroll
        for (int j = 0; j < 16; ++j) {
            float z = acc[j] * inv + bias[c * 16 + j];
            zz.s[j] = f2bf(z > 0.f ? z : 0.f);
        }
        *(bf16x8*)(z_bf + (size_t)i * HC + c * 16)     = zz.v[0];
        *(bf16x8*)(z_bf + (size_t)i * HC + c * 16 + 8) = zz.v[1];
    }
}

__global__ __launch_bounds__(256) void agg2_kernel(const unsigned char* __restrict__ h8,
    const _Float16* __restrict__ wq, const int* __restrict__ row_ptr,
    const int2* __restrict__ es, const float* __restrict__ b2,
    const float* __restrict__ Wp, const float* __restrict__ bp,
    float* __restrict__ out, int N)
{
    const int l  = threadIdx.x & 63;
    const int i  = blockIdx.x * 4 + (threadIdx.x >> 6);
    if (i >= N) return;
    const int c  = l & 15;
    const int eo = l >> 4;
    const int hh = c >> 1;
    const int beg = row_ptr[i], end = row_ptr[i + 1];

    float acc[16];
    #pragma unroll
    for (int j = 0; j < 16; ++j) acc[j] = 0.f;
    float dsum = 0.f;

    int p = beg;
    for (; p + 7 < end; p += 8) {
        int p0 = p + eo, p1 = p + 4 + eo;
        int s0 = es[p0].x, s1 = es[p1].x;
        float w0 = (float)wq[(size_t)p0 * 8 + hh];
        float w1 = (float)wq[(size_t)p1 * 8 + hh];
        uint4 h0 = *(const uint4*)(h8 + (size_t)s0 * 256 + c * 16);
        uint4 h1 = *(const uint4*)(h8 + (size_t)s1 * 256 + c * 16);
        ACC4(h0.x, w0, 0); ACC4(h0.y, w0, 4); ACC4(h0.z, w0, 8); ACC4(h0.w, w0, 12);
        ACC4(h1.x, w1, 0); ACC4(h1.y, w1, 4); ACC4(h1.z, w1, 8); ACC4(h1.w, w1, 12);
        dsum += w0 + w1;
    }
    for (; p < end; p += 4) {
        int pe = p + eo;
        int pc = pe < end ? pe : end - 1;
        int s0 = es[pc].x;
        float w0 = pe < end ? (float)wq[(size_t)pc * 8 + hh] : 0.f;
        uint4 h0 = *(const uint4*)(h8 + (size_t)s0 * 256 + c * 16);
        ACC4(h0.x, w0, 0); ACC4(h0.y, w0, 4); ACC4(h0.z, w0, 8); ACC4(h0.w, w0, 12);
        dsum += w0;
    }

    #pragma unroll
    for (int j = 0; j < 16; ++j) {
        acc[j] += __shfl_xor(acc[j], 32);
        acc[j] += __shfl_xor(acc[j], 16);
    }
    dsum += __shfl_xor(dsum, 32);
    dsum += __shfl_xor(dsum, 16);

    float inv = 1.f / (dsum + 1e-16f);
    const int wb = (c & 1) << 4;     // Wp index base = (16c+j) & 31
    float partial = 0.f;
    #pragma unroll
    for (int j = 0; j < 16; ++j) partial = fmaf(acc[j] * inv, Wp[wb + j], partial);
    if (eo == 0 && c < 2) {
        #pragma unroll
        for (int j = 0; j < 16; ++j) partial += 8.f * b2[c * 16 + j] * Wp[c * 16 + j];
    }
    #pragma unroll
    for (int off = 8; off > 0; off >>= 1) partial += __shfl_xor(partial, off);
    if (l == 0) out[i] = 1.f / (1.f + __expf(-(0.125f * partial + bp[0])));
}

// ---------------------------------------------------------------------------
extern "C" void kernel_launch(void* const* d_in, const int* in_sizes, int n_in,
                              void* d_out, int out_size, void* d_ws, size_t ws_size,
                              hipStream_t stream)
{
    const int*   ei  = (const int*)d_in[0];
    const float* x   = (const float*)d_in[1];
    const float* W1  = (const float*)d_in[2];
    const float* as1 = (const float*)d_in[3];
    const float* ad1 = (const float*)d_in[4];
    const float* b1  = (const float*)d_in[5];
    const float* W2  = (const float*)d_in[6];
    const float* as2 = (const float*)d_in[7];
    const float* ad2 = (const float*)d_in[8];
    const float* b2  = (const float*)d_in[9];
    const float* Wp  = (const float*)d_in[10];
    const float* bp  = (const float*)d_in[11];
    float* out = (float*)d_out;

    const int E = in_sizes[0] / 2;
    const int N = in_sizes[1] / F_IN;
    const int ET = E + N;

    // workspace layout (16B-aligned sections)
    float*         asb = (float*)d_ws;                           // N*8 f32
    float*         adb = asb + (size_t)N * H_HEADS;              // N*8 f32
    unsigned char* h8  = (unsigned char*)(adb + (size_t)N * H_HEADS); // N*256 fp8
    short*         z1b = (short*)(h8 + (size_t)N * HC);          // N*256 bf16
    short*         Wf1 = z1b + (size_t)N * HC;                   // 512*256 bf16
    short*         Wf2 = Wf1 + (size_t)F_IN * HC;                // 256*256 bf16
    _Float16*      wq  = (_Float16*)(Wf2 + (size_t)HC * HC);     // (E+N)*8 fp16
    int2*          es  = (int2*)(wq + (size_t)ET * H_HEADS);     // (E+N) int2
    int* cnt       = (int*)(es + ET);                            // N
    int* row_ptr   = cnt + N;                                    // N+1
    int* chunk_sum = row_ptr + N + 1;                            // 64

    const int NCH = (N + 1023) / 1024;
    const int MB  = (N + 63) / 64;
    const int NB4 = (N + 3) / 4;

    // ---- CSR build ----
    zero_int<<<(N + 255) / 256, 256, 0, stream>>>(cnt, N);
    hist_kernel<<<(ET + 255) / 256, 256, 0, stream>>>(ei, E, N, cnt);
    scan_sum<<<NCH, 256, 0, stream>>>(cnt, N, chunk_sum);
    scan_local<<<NCH, 256, 0, stream>>>(cnt, N, chunk_sum, NCH, row_ptr);
    scatter_kernel<<<(ET + 255) / 256, 256, 0, stream>>>(ei, E, N, row_ptr, cnt, es);

    // ---- W repack ----
    wfrag_kernel<<<(F_IN * HC + 255) / 256, 256, 0, stream>>>(W1, Wf1, F_IN);
    wfrag_kernel<<<(HC * HC + 255) / 256, 256, 0, stream>>>(W2, Wf2, HC);

    // ---- Layer 1 ----
    gemm_mfma<false><<<MB, 256, 0, stream>>>(x, Wf1, h8, as1, ad1, asb, adb, N, F_IN);
    wcalc_kernel<<<(ET + 255) / 256, 256, 0, stream>>>(es, asb, adb, wq, ET);
    agg1_kernel<<<NB4, 256, 0, stream>>>(h8, wq, row_ptr, es, b1, z1b, N);

    // ---- Layer 2 ----
    gemm_mfma<true><<<MB, 256, 0, stream>>>(z1b, Wf2, h8, as2, ad2, asb, adb, N, HC);
    wcalc_kernel<<<(ET + 255) / 256, 256, 0, stream>>>(es, asb, adb, wq, ET);
    agg2_kernel<<<NB4, 256, 0, stream>>>(h8, wq, row_ptr, es, b2, Wp, bp, out, N);
}

// Round 7
// 404.505 us; speedup vs baseline: 1.3341x; 1.0381x over previous
//
#include <hip/hip_runtime.h>
#include <math.h>

#define H_HEADS 8
#define C_DIM   32
#define HC      256
#define F_IN    512
#define NEG_SLOPE 0.2f

typedef __attribute__((ext_vector_type(8))) short    bf16x8;
typedef __attribute__((ext_vector_type(4))) short    s16x4;
typedef __attribute__((ext_vector_type(4))) float    f32x4;
typedef __attribute__((ext_vector_type(2))) float    f32x2;

__device__ __forceinline__ short f2bf(float f) {
    union { float f; unsigned u; } v; v.f = f;
    unsigned r = v.u + 0x7FFF + ((v.u >> 16) & 1);   // RNE
    return (short)(r >> 16);
}

// packed fp32->bf16 (RNE), 8 elems in 4 instructions
__device__ __forceinline__ bf16x8 cvt8(float4 a, float4 b) {
    union { bf16x8 v; unsigned u[4]; } r;
    asm("v_cvt_pk_bf16_f32 %0, %1, %2" : "=v"(r.u[0]) : "v"(a.x), "v"(a.y));
    asm("v_cvt_pk_bf16_f32 %0, %1, %2" : "=v"(r.u[1]) : "v"(a.z), "v"(a.w));
    asm("v_cvt_pk_bf16_f32 %0, %1, %2" : "=v"(r.u[2]) : "v"(b.x), "v"(b.y));
    asm("v_cvt_pk_bf16_f32 %0, %1, %2" : "=v"(r.u[3]) : "v"(b.z), "v"(b.w));
    return r.v;
}

__device__ __forceinline__ void gl2lds16(const short* g, short* l) {
    __builtin_amdgcn_global_load_lds(
        (const __attribute__((address_space(1))) void*)g,
        (__attribute__((address_space(3))) void*)l, 16, 0, 0);
}

// ---------------------------------------------------------------------------
// Repack W1+W2 [K,256] fp32 -> MFMA B-frag-ordered bf16, single launch.
// ---------------------------------------------------------------------------
__global__ void wfrag_kernel(const float* __restrict__ W1, const float* __restrict__ W2,
                             short* __restrict__ Wf1, short* __restrict__ Wf2)
{
    const int NW1 = F_IN * HC;
    const int NW2 = HC * HC;
    int tid = blockIdx.x * 256 + threadIdx.x;
    const float* W; short* Wf; int t;
    if (tid < NW1)            { W = W1; Wf = Wf1; t = tid; }
    else if (tid < NW1 + NW2) { W = W2; Wf = Wf2; t = tid - NW1; }
    else return;
    int j  = t & 7;
    int l  = (t >> 3) & 63;
    int nb = (t >> 9) & 15;
    int s  = t >> 13;
    int k  = s * 32 + (l >> 4) * 8 + j;
    int n  = nb * 16 + (l & 15);
    Wf[t] = f2bf(W[(size_t)k * HC + n]);
}

// ---------------------------------------------------------------------------
// MFMA GEMM + fused epilogue — r0 structure (67 us verified; frozen).
// Only change: fp32->bf16 A conversion via v_cvt_pk (24 VALU ops -> 4).
// ---------------------------------------------------------------------------
template<bool ABF16>
__global__ __launch_bounds__(256) void gemm_mfma(const void* __restrict__ Aptr,
    const short* __restrict__ Bf, unsigned char* __restrict__ h8,
    const float* __restrict__ a_s, const float* __restrict__ a_d,
    float* __restrict__ alpha_s, float* __restrict__ alpha_d, int M, int K)
{
    __shared__ short Bs[2][8192];            // 2 x 16 KB K-step tiles
    __shared__ float Als[512], Ald[512];     // 64 rows x 8 heads

    const int tid  = threadIdx.x;
    const int w    = tid >> 6;
    const int lane = tid & 63;
    const int quad = lane >> 4;
    const int ml   = lane & 15;
    const int bm   = blockIdx.x * 64;

    const int rowA = bm + w * 16 + ml;
    const int rowL = rowA < M ? rowA : M - 1;

    f32x4 acc[16];
    #pragma unroll
    for (int nb = 0; nb < 16; ++nb) acc[nb] = (f32x4){0.f, 0.f, 0.f, 0.f};

    const float* A32 = (const float*)Aptr;
    const short* A16 = (const short*)Aptr;
    const int nsteps = K >> 5;

    {   // stage B step 0
        const short* g = Bf + (size_t)w * 2048 + lane * 8;
        short* l = &Bs[0][w * 2048];
        #pragma unroll
        for (int c = 0; c < 4; ++c) gl2lds16(g + c * 512, l + c * 512);
    }

    float4 p0, p1;
    bf16x8 pb;
    if (ABF16) {
        pb = *(const bf16x8*)(A16 + (size_t)rowL * K + quad * 8);
    } else {
        const float* ap = A32 + (size_t)rowL * K + quad * 8;
        p0 = *(const float4*)(ap);
        p1 = *(const float4*)(ap + 4);
    }

    for (int s = 0; s < nsteps; ++s) {
        __syncthreads();

        if (s + 1 < nsteps) {
            const short* g = Bf + (size_t)(s + 1) * 8192 + w * 2048 + lane * 8;
            short* l = &Bs[(s + 1) & 1][w * 2048];
            #pragma unroll
            for (int c = 0; c < 4; ++c) gl2lds16(g + c * 512, l + c * 512);
        }

        bf16x8 af;
        if (ABF16) {
            af = pb;
            if (s + 1 < nsteps)
                pb = *(const bf16x8*)(A16 + (size_t)rowL * K + (s + 1) * 32 + quad * 8);
        } else {
            af = cvt8(p0, p1);
            if (s + 1 < nsteps) {
                const float* ap = A32 + (size_t)rowL * K + (s + 1) * 32 + quad * 8;
                p0 = *(const float4*)(ap);
                p1 = *(const float4*)(ap + 4);
            }
        }

        const short* bsrc = &Bs[s & 1][lane * 8];
        #pragma unroll
        for (int nb = 0; nb < 16; ++nb) {
            bf16x8 bfr = *(const bf16x8*)(bsrc + nb * 512);
            acc[nb] = __builtin_amdgcn_mfma_f32_16x16x32_bf16(af, bfr, acc[nb], 0, 0, 0);
        }
    }

    // ---- epilogue: fp8 store + fused per-head alpha dots ----
    float as_v[16], ad_v[16];
    #pragma unroll
    for (int nb = 0; nb < 16; ++nb) {
        as_v[nb] = a_s[nb * 16 + ml];
        ad_v[nb] = a_d[nb * 16 + ml];
    }

    #pragma unroll
    for (int r = 0; r < 4; ++r) {
        const int rl  = w * 16 + quad * 4 + r;
        const int row = bm + rl;

        if (row < M) {
            unsigned char* hrow = h8 + (size_t)row * HC;
            #pragma unroll
            for (int i = 0; i < 8; ++i) {
                int pk = __builtin_amdgcn_cvt_pk_fp8_f32(acc[2 * i][r], acc[2 * i + 1][r], 0, false);
                hrow[(2 * i) * 16 + ml]     = (unsigned char)(pk & 0xFF);
                hrow[(2 * i + 1) * 16 + ml] = (unsigned char)((pk >> 8) & 0xFF);
            }
        }

        float hs[8], hd[8];
        #pragma unroll
        for (int q = 0; q < 8; ++q) {
            hs[q] = acc[2 * q][r] * as_v[2 * q] + acc[2 * q + 1][r] * as_v[2 * q + 1];
            hd[q] = acc[2 * q][r] * ad_v[2 * q] + acc[2 * q + 1][r] * ad_v[2 * q + 1];
        }
        #pragma unroll
        for (int off = 1; off < 16; off <<= 1) {
            #pragma unroll
            for (int q = 0; q < 8; ++q) {
                hs[q] += __shfl_xor(hs[q], off);
                hd[q] += __shfl_xor(hd[q], off);
            }
        }
        if (ml == 0) {
            #pragma unroll
            for (int q = 0; q < 8; ++q) {
                Als[rl * 8 + q] = hs[q];
                Ald[rl * 8 + q] = hd[q];
            }
        }
    }
    __syncthreads();
    #pragma unroll
    for (int k = 0; k < 2; ++k) {
        int idx = tid + k * 256;
        int rl = idx >> 3, q = idx & 7;
        int row = bm + rl;
        if (row < M) {
            alpha_s[(size_t)row * H_HEADS + q] = Als[idx];
            alpha_d[(size_t)row * H_HEADS + q] = Ald[idx];
        }
    }
}

// ---------------------------------------------------------------------------
// CSR build
// ---------------------------------------------------------------------------
__global__ void zero_int(int* __restrict__ p, int n)
{
    int i = blockIdx.x * 256 + threadIdx.x;
    if (i < n) p[i] = 0;
}

__global__ void hist_kernel(const int* __restrict__ ei, int E, int N,
                            int* __restrict__ cnt)
{
    int e = blockIdx.x * 256 + threadIdx.x;
    if (e < E) atomicAdd(&cnt[ei[E + e]], 1);
    else if (e < E + N) atomicAdd(&cnt[e - E], 1);
}

__global__ __launch_bounds__(256) void scan_sum(const int* __restrict__ cnt, int n,
                                                int* __restrict__ chunk_sum)
{
    __shared__ int lds[256];
    int b = blockIdx.x, t = threadIdx.x;
    int base = b * 1024 + t * 4;
    int s = 0;
    #pragma unroll
    for (int j = 0; j < 4; ++j) { int i = base + j; if (i < n) s += cnt[i]; }
    lds[t] = s; __syncthreads();
    for (int off = 128; off > 0; off >>= 1) {
        if (t < off) lds[t] += lds[t + off];
        __syncthreads();
    }
    if (t == 0) chunk_sum[b] = lds[0];
}

// scan_local with inlined chunk-offset reduce (each wave reduces <=64 sums).
__global__ __launch_bounds__(256) void scan_local(const int* __restrict__ cnt, int n,
    const int* __restrict__ chunk_sum, int nch, int* __restrict__ row_ptr)
{
    __shared__ int lds[256];
    int b = blockIdx.x, t = threadIdx.x;
    int lane = t & 63;

    int cs  = (lane < nch) ? chunk_sum[lane] : 0;
    int pre = (lane < b)   ? cs : 0;
    int tot = cs;
    #pragma unroll
    for (int off = 32; off > 0; off >>= 1) {
        pre += __shfl_xor(pre, off);
        tot += __shfl_xor(tot, off);
    }

    int base = b * 1024 + t * 4;
    int v[4]; int s = 0;
    #pragma unroll
    for (int j = 0; j < 4; ++j) { int i = base + j; v[j] = (i < n) ? cnt[i] : 0; s += v[j]; }
    lds[t] = s; __syncthreads();
    for (int off = 1; off < 256; off <<= 1) {
        int u = (t >= off) ? lds[t - off] : 0;
        __syncthreads();
        lds[t] += u;
        __syncthreads();
    }
    int run = lds[t] - s + pre;
    #pragma unroll
    for (int j = 0; j < 4; ++j) {
        int i = base + j;
        if (i < n) row_ptr[i] = run;
        run += v[j];
    }
    if (b == gridDim.x - 1 && t == 0) row_ptr[n] = tot;
}

// Reverse-fill scatter: consumes cnt (atomicSub). src-only payload (agg needs
// only the source node now that wcalc is fused into agg).
__global__ void scatter_kernel(const int* __restrict__ ei, int E, int N,
    const int* __restrict__ row_ptr, int* __restrict__ cnt, int* __restrict__ es)
{
    int e = blockIdx.x * 256 + threadIdx.x;
    int src, dst;
    if (e < E)          { src = ei[e]; dst = ei[E + e]; }
    else if (e < E + N) { src = dst = e - E; }
    else return;
    int pos = row_ptr[dst] + atomicSub(&cnt[dst], 1) - 1;
    es[pos] = src;
}

// ---------------------------------------------------------------------------
// Aggregation with wcalc FUSED, 4-edges-per-wave layout:
//   lane l: edge slot eo = l>>4 (4 concurrent edges), channel quad c = l&15
//   per edge: w = exp(leaky(asb[src*8+h] + adb[dst*8+h]))  (asb 1.6 MB =
//   L2-resident gather; adb term is loop-invariant per node)
//   gather = one dwordx4 (16 fp8 channels) per lane per edge.
// End of loop: acc/dsum summed across the 4 slots via 2 shfl_xor levels.
// ---------------------------------------------------------------------------
#define ACC4(word, wgt, base_) do { \
    f32x2 lo_ = __builtin_amdgcn_cvt_pk_f32_fp8((word), false); \
    f32x2 hi_ = __builtin_amdgcn_cvt_pk_f32_fp8((word), true);  \
    acc[(base_) + 0] = fmaf((wgt), lo_[0], acc[(base_) + 0]); \
    acc[(base_) + 1] = fmaf((wgt), lo_[1], acc[(base_) + 1]); \
    acc[(base_) + 2] = fmaf((wgt), hi_[0], acc[(base_) + 2]); \
    acc[(base_) + 3] = fmaf((wgt), hi_[1], acc[(base_) + 3]); \
} while (0)

__device__ __forceinline__ float edge_w(float av, float ad8) {
    float e = av + ad8;
    return __expf(e > 0.f ? e : NEG_SLOPE * e);
}

__global__ __launch_bounds__(256) void agg1_kernel(const unsigned char* __restrict__ h8,
    const float* __restrict__ asb, const float* __restrict__ adb,
    const int* __restrict__ row_ptr, const int* __restrict__ es,
    const float* __restrict__ bias, short* __restrict__ z_bf, int N)
{
    const int l  = threadIdx.x & 63;
    const int i  = blockIdx.x * 4 + (threadIdx.x >> 6);
    if (i >= N) return;
    const int c  = l & 15;      // channels 16c..16c+15
    const int eo = l >> 4;      // edge slot
    const int hh = c >> 1;      // head of this lane's channels
    const float ad8 = adb[(size_t)i * 8 + hh];
    const int beg = row_ptr[i], end = row_ptr[i + 1];

    float acc[16];
    #pragma unroll
    for (int j = 0; j < 16; ++j) acc[j] = 0.f;
    float dsum = 0.f;

    int p = beg;
    for (; p + 7 < end; p += 8) {
        int s0 = es[p + eo], s1 = es[p + 4 + eo];
        float a0 = asb[(size_t)s0 * 8 + hh];
        float a1 = asb[(size_t)s1 * 8 + hh];
        uint4 h0 = *(const uint4*)(h8 + (size_t)s0 * 256 + c * 16);
        uint4 h1 = *(const uint4*)(h8 + (size_t)s1 * 256 + c * 16);
        float w0 = edge_w(a0, ad8);
        float w1 = edge_w(a1, ad8);
        ACC4(h0.x, w0, 0); ACC4(h0.y, w0, 4); ACC4(h0.z, w0, 8); ACC4(h0.w, w0, 12);
        ACC4(h1.x, w1, 0); ACC4(h1.y, w1, 4); ACC4(h1.z, w1, 8); ACC4(h1.w, w1, 12);
        dsum += w0 + w1;
    }
    for (; p < end; p += 4) {
        int pe = p + eo;
        int pc = pe < end ? pe : end - 1;
        int s0 = es[pc];
        float w0 = pe < end ? edge_w(asb[(size_t)s0 * 8 + hh], ad8) : 0.f;
        uint4 h0 = *(const uint4*)(h8 + (size_t)s0 * 256 + c * 16);
        ACC4(h0.x, w0, 0); ACC4(h0.y, w0, 4); ACC4(h0.z, w0, 8); ACC4(h0.w, w0, 12);
        dsum += w0;
    }

    #pragma unroll
    for (int j = 0; j < 16; ++j) {
        acc[j] += __shfl_xor(acc[j], 32);
        acc[j] += __shfl_xor(acc[j], 16);
    }
    dsum += __shfl_xor(dsum, 32);
    dsum += __shfl_xor(dsum, 16);

    float inv = 1.f / (dsum + 1e-16f);
    if (eo == 0) {
        union { short s[16]; bf16x8 v[2]; } zz;
        #pragma unroll
        for (int j = 0; j < 16; ++j) {
            float z = acc[j] * inv + bias[c * 16 + j];
            zz.s[j] = f2bf(z > 0.f ? z : 0.f);
        }
        *(bf16x8*)(z_bf + (size_t)i * HC + c * 16)     = zz.v[0];
        *(bf16x8*)(z_bf + (size_t)i * HC + c * 16 + 8) = zz.v[1];
    }
}

__global__ __launch_bounds__(256) void agg2_kernel(const unsigned char* __restrict__ h8,
    const float* __restrict__ asb, const float* __restrict__ adb,
    const int* __restrict__ row_ptr, const int* __restrict__ es,
    const float* __restrict__ b2, const float* __restrict__ Wp,
    const float* __restrict__ bp, float* __restrict__ out, int N)
{
    const int l  = threadIdx.x & 63;
    const int i  = blockIdx.x * 4 + (threadIdx.x >> 6);
    if (i >= N) return;
    const int c  = l & 15;
    const int eo = l >> 4;
    const int hh = c >> 1;
    const float ad8 = adb[(size_t)i * 8 + hh];
    const int beg = row_ptr[i], end = row_ptr[i + 1];

    float acc[16];
    #pragma unroll
    for (int j = 0; j < 16; ++j) acc[j] = 0.f;
    float dsum = 0.f;

    int p = beg;
    for (; p + 7 < end; p += 8) {
        int s0 = es[p + eo], s1 = es[p + 4 + eo];
        float a0 = asb[(size_t)s0 * 8 + hh];
        float a1 = asb[(size_t)s1 * 8 + hh];
        uint4 h0 = *(const uint4*)(h8 + (size_t)s0 * 256 + c * 16);
        uint4 h1 = *(const uint4*)(h8 + (size_t)s1 * 256 + c * 16);
        float w0 = edge_w(a0, ad8);
        float w1 = edge_w(a1, ad8);
        ACC4(h0.x, w0, 0); ACC4(h0.y, w0, 4); ACC4(h0.z, w0, 8); ACC4(h0.w, w0, 12);
        ACC4(h1.x, w1, 0); ACC4(h1.y, w1, 4); ACC4(h1.z, w1, 8); ACC4(h1.w, w1, 12);
        dsum += w0 + w1;
    }
    for (; p < end; p += 4) {
        int pe = p + eo;
        int pc = pe < end ? pe : end - 1;
        int s0 = es[pc];
        float w0 = pe < end ? edge_w(asb[(size_t)s0 * 8 + hh], ad8) : 0.f;
        uint4 h0 = *(const uint4*)(h8 + (size_t)s0 * 256 + c * 16);
        ACC4(h0.x, w0, 0); ACC4(h0.y, w0, 4); ACC4(h0.z, w0, 8); ACC4(h0.w, w0, 12);
        dsum += w0;
    }

    #pragma unroll
    for (int j = 0; j < 16; ++j) {
        acc[j] += __shfl_xor(acc[j], 32);
        acc[j] += __shfl_xor(acc[j], 16);
    }
    dsum += __shfl_xor(dsum, 32);
    dsum += __shfl_xor(dsum, 16);

    float inv = 1.f / (dsum + 1e-16f);
    const int wb = (c & 1) << 4;     // Wp index base = (16c+j) & 31
    float partial = 0.f;
    #pragma unroll
    for (int j = 0; j < 16; ++j) partial = fmaf(acc[j] * inv, Wp[wb + j], partial);
    if (eo == 0 && c < 2) {
        #pragma unroll
        for (int j = 0; j < 16; ++j) partial += 8.f * b2[c * 16 + j] * Wp[c * 16 + j];
    }
    #pragma unroll
    for (int off = 8; off > 0; off >>= 1) partial += __shfl_xor(partial, off);
    if (l == 0) out[i] = 1.f / (1.f + __expf(-(0.125f * partial + bp[0])));
}

// ---------------------------------------------------------------------------
extern "C" void kernel_launch(void* const* d_in, const int* in_sizes, int n_in,
                              void* d_out, int out_size, void* d_ws, size_t ws_size,
                              hipStream_t stream)
{
    const int*   ei  = (const int*)d_in[0];
    const float* x   = (const float*)d_in[1];
    const float* W1  = (const float*)d_in[2];
    const float* as1 = (const float*)d_in[3];
    const float* ad1 = (const float*)d_in[4];
    const float* b1  = (const float*)d_in[5];
    const float* W2  = (const float*)d_in[6];
    const float* as2 = (const float*)d_in[7];
    const float* ad2 = (const float*)d_in[8];
    const float* b2  = (const float*)d_in[9];
    const float* Wp  = (const float*)d_in[10];
    const float* bp  = (const float*)d_in[11];
    float* out = (float*)d_out;

    const int E = in_sizes[0] / 2;
    const int N = in_sizes[1] / F_IN;
    const int ET = E + N;

    // workspace layout (16B-aligned sections)
    float*         asb = (float*)d_ws;                           // N*8 f32
    float*         adb = asb + (size_t)N * H_HEADS;              // N*8 f32
    unsigned char* h8  = (unsigned char*)(adb + (size_t)N * H_HEADS); // N*256 fp8
    short*         z1b = (short*)(h8 + (size_t)N * HC);          // N*256 bf16
    short*         Wf1 = z1b + (size_t)N * HC;                   // 512*256 bf16
    short*         Wf2 = Wf1 + (size_t)F_IN * HC;                // 256*256 bf16
    int*           es  = (int*)(Wf2 + (size_t)HC * HC);          // (E+N) int (src)
    int* cnt       = es + ET;                                    // N
    int* row_ptr   = cnt + N;                                    // N+1
    int* chunk_sum = row_ptr + N + 1;                            // 64

    const int NCH = (N + 1023) / 1024;
    const int MB  = (N + 63) / 64;
    const int NB4 = (N + 3) / 4;

    // ---- CSR build ----
    zero_int<<<(N + 255) / 256, 256, 0, stream>>>(cnt, N);
    hist_kernel<<<(ET + 255) / 256, 256, 0, stream>>>(ei, E, N, cnt);
    scan_sum<<<NCH, 256, 0, stream>>>(cnt, N, chunk_sum);
    scan_local<<<NCH, 256, 0, stream>>>(cnt, N, chunk_sum, NCH, row_ptr);
    scatter_kernel<<<(ET + 255) / 256, 256, 0, stream>>>(ei, E, N, row_ptr, cnt, es);

    // ---- W repack (single launch) ----
    wfrag_kernel<<<(F_IN * HC + HC * HC + 255) / 256, 256, 0, stream>>>(W1, W2, Wf1, Wf2);

    // ---- Layer 1 ----
    gemm_mfma<false><<<MB, 256, 0, stream>>>(x, Wf1, h8, as1, ad1, asb, adb, N, F_IN);
    agg1_kernel<<<NB4, 256, 0, stream>>>(h8, asb, adb, row_ptr, es, b1, z1b, N);

    // ---- Layer 2 ----
    gemm_mfma<true><<<MB, 256, 0, stream>>>(z1b, Wf2, h8, as2, ad2, asb, adb, N, HC);
    agg2_kernel<<<NB4, 256, 0, stream>>>(h8, asb, adb, row_ptr, es, b2, Wp, bp, out, N);
}

// Round 8
// 399.776 us; speedup vs baseline: 1.3499x; 1.0118x over previous
//
#include <hip/hip_runtime.h>
#include <math.h>

#define H_HEADS 8
#define C_DIM   32
#define HC      256
#define F_IN    512
#define NEG_SLOPE 0.2f

typedef __attribute__((ext_vector_type(8))) short    bf16x8;
typedef __attribute__((ext_vector_type(4))) short    s16x4;
typedef __attribute__((ext_vector_type(4))) float    f32x4;
typedef __attribute__((ext_vector_type(2))) float    f32x2;

__device__ __forceinline__ short f2bf(float f) {
    union { float f; unsigned u; } v; v.f = f;
    unsigned r = v.u + 0x7FFF + ((v.u >> 16) & 1);   // RNE
    return (short)(r >> 16);
}

// packed fp32->bf16 (RNE), 8 elems in 4 instructions
__device__ __forceinline__ bf16x8 cvt8(float4 a, float4 b) {
    union { bf16x8 v; unsigned u[4]; } r;
    asm("v_cvt_pk_bf16_f32 %0, %1, %2" : "=v"(r.u[0]) : "v"(a.x), "v"(a.y));
    asm("v_cvt_pk_bf16_f32 %0, %1, %2" : "=v"(r.u[1]) : "v"(a.z), "v"(a.w));
    asm("v_cvt_pk_bf16_f32 %0, %1, %2" : "=v"(r.u[2]) : "v"(b.x), "v"(b.y));
    asm("v_cvt_pk_bf16_f32 %0, %1, %2" : "=v"(r.u[3]) : "v"(b.z), "v"(b.w));
    return r.v;
}

__device__ __forceinline__ void gl2lds16(const short* g, short* l) {
    __builtin_amdgcn_global_load_lds(
        (const __attribute__((address_space(1))) void*)g,
        (__attribute__((address_space(3))) void*)l, 16, 0, 0);
}

// ---------------------------------------------------------------------------
// Repack W1+W2 [K,256] fp32 -> MFMA B-frag-ordered bf16, single launch.
// ---------------------------------------------------------------------------
__global__ void wfrag_kernel(const float* __restrict__ W1, const float* __restrict__ W2,
                             short* __restrict__ Wf1, short* __restrict__ Wf2)
{
    const int NW1 = F_IN * HC;
    const int NW2 = HC * HC;
    int tid = blockIdx.x * 256 + threadIdx.x;
    const float* W; short* Wf; int t;
    if (tid < NW1)            { W = W1; Wf = Wf1; t = tid; }
    else if (tid < NW1 + NW2) { W = W2; Wf = Wf2; t = tid - NW1; }
    else return;
    int j  = t & 7;
    int l  = (t >> 3) & 63;
    int nb = (t >> 9) & 15;
    int s  = t >> 13;
    int k  = s * 32 + (l >> 4) * 8 + j;
    int n  = nb * 16 + (l & 15);
    Wf[t] = f2bf(W[(size_t)k * HC + n]);
}

// ---------------------------------------------------------------------------
// MFMA GEMM + fused epilogue — r0 loop structure, N-SPLIT for TLP:
// each block computes 64 rows x 128 cols (column half cb); grid = stripes x 2.
// 18 KB LDS -> ~6 blocks/CU co-resident (was 3): the per-phase barrier+drain
// chains of different blocks interleave on the CU, hiding the latency that
// five schedule rewrites (r1-r5) could not remove.
// Column half cb covers heads cb*4..cb*4+3 exactly -> alpha dots stay local.
// ---------------------------------------------------------------------------
template<bool ABF16>
__global__ __launch_bounds__(256) void gemm_mfma(const void* __restrict__ Aptr,
    const short* __restrict__ Bf, unsigned char* __restrict__ h8,
    const float* __restrict__ a_s, const float* __restrict__ a_d,
    float* __restrict__ alpha_s, float* __restrict__ alpha_d, int M, int K)
{
    __shared__ short Bs[2][4096];            // 2 x 8 KB half-width K-step tiles
    __shared__ float Als[256], Ald[256];     // 64 rows x 4 heads

    const int tid  = threadIdx.x;
    const int w    = tid >> 6;
    const int lane = tid & 63;
    const int quad = lane >> 4;
    const int ml   = lane & 15;
    const int cb   = blockIdx.x & 1;         // column half (pair shares A rows)
    const int bm   = (blockIdx.x >> 1) * 64;

    const int rowA = bm + w * 16 + ml;
    const int rowL = rowA < M ? rowA : M - 1;

    f32x4 acc[8];
    #pragma unroll
    for (int nb = 0; nb < 8; ++nb) acc[nb] = (f32x4){0.f, 0.f, 0.f, 0.f};

    const float* A32 = (const float*)Aptr;
    const short* A16 = (const short*)Aptr;
    const int nsteps = K >> 5;

    {   // stage B step 0 (half: 8 KB = 2 x 16B per thread)
        const short* g = Bf + (size_t)cb * 4096 + w * 512 + lane * 8;
        short* l = &Bs[0][w * 512 + lane * 8];
        gl2lds16(g, l);
        gl2lds16(g + 2048, l + 2048);
    }

    float4 p0, p1;
    bf16x8 pb;
    if (ABF16) {
        pb = *(const bf16x8*)(A16 + (size_t)rowL * K + quad * 8);
    } else {
        const float* ap = A32 + (size_t)rowL * K + quad * 8;
        p0 = *(const float4*)(ap);
        p1 = *(const float4*)(ap + 4);
    }

    for (int s = 0; s < nsteps; ++s) {
        __syncthreads();

        if (s + 1 < nsteps) {
            const short* g = Bf + (size_t)(s + 1) * 8192 + cb * 4096 + w * 512 + lane * 8;
            short* l = &Bs[(s + 1) & 1][w * 512 + lane * 8];
            gl2lds16(g, l);
            gl2lds16(g + 2048, l + 2048);
        }

        bf16x8 af;
        if (ABF16) {
            af = pb;
            if (s + 1 < nsteps)
                pb = *(const bf16x8*)(A16 + (size_t)rowL * K + (s + 1) * 32 + quad * 8);
        } else {
            af = cvt8(p0, p1);
            if (s + 1 < nsteps) {
                const float* ap = A32 + (size_t)rowL * K + (s + 1) * 32 + quad * 8;
                p0 = *(const float4*)(ap);
                p1 = *(const float4*)(ap + 4);
            }
        }

        const short* bsrc = &Bs[s & 1][lane * 8];
        #pragma unroll
        for (int nb = 0; nb < 8; ++nb) {
            bf16x8 bfr = *(const bf16x8*)(bsrc + nb * 512);
            acc[nb] = __builtin_amdgcn_mfma_f32_16x16x32_bf16(af, bfr, acc[nb], 0, 0, 0);
        }
    }

    // ---- epilogue: fp8 store + fused per-head alpha dots (4 heads/block) ----
    // lane owns cols c = cb*128 + nb*16 + ml for rows bm + w*16 + quad*4 + r
    float as_v[8], ad_v[8];
    #pragma unroll
    for (int nb = 0; nb < 8; ++nb) {
        as_v[nb] = a_s[cb * 128 + nb * 16 + ml];
        ad_v[nb] = a_d[cb * 128 + nb * 16 + ml];
    }

    #pragma unroll
    for (int r = 0; r < 4; ++r) {
        const int rl  = w * 16 + quad * 4 + r;
        const int row = bm + rl;

        if (row < M) {
            unsigned char* hrow = h8 + (size_t)row * HC + cb * 128;
            #pragma unroll
            for (int i = 0; i < 4; ++i) {
                int pk = __builtin_amdgcn_cvt_pk_fp8_f32(acc[2 * i][r], acc[2 * i + 1][r], 0, false);
                hrow[(2 * i) * 16 + ml]     = (unsigned char)(pk & 0xFF);
                hrow[(2 * i + 1) * 16 + ml] = (unsigned char)((pk >> 8) & 0xFF);
            }
        }

        float hs[4], hd[4];
        #pragma unroll
        for (int q = 0; q < 4; ++q) {
            hs[q] = acc[2 * q][r] * as_v[2 * q] + acc[2 * q + 1][r] * as_v[2 * q + 1];
            hd[q] = acc[2 * q][r] * ad_v[2 * q] + acc[2 * q + 1][r] * ad_v[2 * q + 1];
        }
        #pragma unroll
        for (int off = 1; off < 16; off <<= 1) {
            #pragma unroll
            for (int q = 0; q < 4; ++q) {
                hs[q] += __shfl_xor(hs[q], off);
                hd[q] += __shfl_xor(hd[q], off);
            }
        }
        if (ml == 0) {
            #pragma unroll
            for (int q = 0; q < 4; ++q) {
                Als[rl * 4 + q] = hs[q];
                Ald[rl * 4 + q] = hd[q];
            }
        }
    }
    __syncthreads();
    {
        int rl = tid >> 2, q = tid & 3;      // 256 = 64 rows x 4 heads
        int row = bm + rl;
        if (row < M) {
            alpha_s[(size_t)row * H_HEADS + cb * 4 + q] = Als[tid];
            alpha_d[(size_t)row * H_HEADS + cb * 4 + q] = Ald[tid];
        }
    }
}

// ---------------------------------------------------------------------------
// CSR build
// ---------------------------------------------------------------------------
__global__ void zero_int(int* __restrict__ p, int n)
{
    int i = blockIdx.x * 256 + threadIdx.x;
    if (i < n) p[i] = 0;
}

__global__ void hist_kernel(const int* __restrict__ ei, int E, int N,
                            int* __restrict__ cnt)
{
    int e = blockIdx.x * 256 + threadIdx.x;
    if (e < E) atomicAdd(&cnt[ei[E + e]], 1);
    else if (e < E + N) atomicAdd(&cnt[e - E], 1);
}

__global__ __launch_bounds__(256) void scan_sum(const int* __restrict__ cnt, int n,
                                                int* __restrict__ chunk_sum)
{
    __shared__ int lds[256];
    int b = blockIdx.x, t = threadIdx.x;
    int base = b * 1024 + t * 4;
    int s = 0;
    #pragma unroll
    for (int j = 0; j < 4; ++j) { int i = base + j; if (i < n) s += cnt[i]; }
    lds[t] = s; __syncthreads();
    for (int off = 128; off > 0; off >>= 1) {
        if (t < off) lds[t] += lds[t + off];
        __syncthreads();
    }
    if (t == 0) chunk_sum[b] = lds[0];
}

// scan_local with inlined chunk-offset reduce (each wave reduces <=64 sums).
__global__ __launch_bounds__(256) void scan_local(const int* __restrict__ cnt, int n,
    const int* __restrict__ chunk_sum, int nch, int* __restrict__ row_ptr)
{
    __shared__ int lds[256];
    int b = blockIdx.x, t = threadIdx.x;
    int lane = t & 63;

    int cs  = (lane < nch) ? chunk_sum[lane] : 0;
    int pre = (lane < b)   ? cs : 0;
    int tot = cs;
    #pragma unroll
    for (int off = 32; off > 0; off >>= 1) {
        pre += __shfl_xor(pre, off);
        tot += __shfl_xor(tot, off);
    }

    int base = b * 1024 + t * 4;
    int v[4]; int s = 0;
    #pragma unroll
    for (int j = 0; j < 4; ++j) { int i = base + j; v[j] = (i < n) ? cnt[i] : 0; s += v[j]; }
    lds[t] = s; __syncthreads();
    for (int off = 1; off < 256; off <<= 1) {
        int u = (t >= off) ? lds[t - off] : 0;
        __syncthreads();
        lds[t] += u;
        __syncthreads();
    }
    int run = lds[t] - s + pre;
    #pragma unroll
    for (int j = 0; j < 4; ++j) {
        int i = base + j;
        if (i < n) row_ptr[i] = run;
        run += v[j];
    }
    if (b == gridDim.x - 1 && t == 0) row_ptr[n] = tot;
}

// Reverse-fill scatter: consumes cnt (atomicSub). src-only payload.
__global__ void scatter_kernel(const int* __restrict__ ei, int E, int N,
    const int* __restrict__ row_ptr, int* __restrict__ cnt, int* __restrict__ es)
{
    int e = blockIdx.x * 256 + threadIdx.x;
    int src, dst;
    if (e < E)          { src = ei[e]; dst = ei[E + e]; }
    else if (e < E + N) { src = dst = e - E; }
    else return;
    int pos = row_ptr[dst] + atomicSub(&cnt[dst], 1) - 1;
    es[pos] = src;
}

// ---------------------------------------------------------------------------
// Aggregation with wcalc FUSED, 4-edges-per-wave layout.
// ---------------------------------------------------------------------------
#define ACC4(word, wgt, base_) do { \
    f32x2 lo_ = __builtin_amdgcn_cvt_pk_f32_fp8((word), false); \
    f32x2 hi_ = __builtin_amdgcn_cvt_pk_f32_fp8((word), true);  \
    acc[(base_) + 0] = fmaf((wgt), lo_[0], acc[(base_) + 0]); \
    acc[(base_) + 1] = fmaf((wgt), lo_[1], acc[(base_) + 1]); \
    acc[(base_) + 2] = fmaf((wgt), hi_[0], acc[(base_) + 2]); \
    acc[(base_) + 3] = fmaf((wgt), hi_[1], acc[(base_) + 3]); \
} while (0)

__device__ __forceinline__ float edge_w(float av, float ad8) {
    float e = av + ad8;
    return __expf(e > 0.f ? e : NEG_SLOPE * e);
}

__global__ __launch_bounds__(256) void agg1_kernel(const unsigned char* __restrict__ h8,
    const float* __restrict__ asb, const float* __restrict__ adb,
    const int* __restrict__ row_ptr, const int* __restrict__ es,
    const float* __restrict__ bias, short* __restrict__ z_bf, int N)
{
    const int l  = threadIdx.x & 63;
    const int i  = blockIdx.x * 4 + (threadIdx.x >> 6);
    if (i >= N) return;
    const int c  = l & 15;      // channels 16c..16c+15
    const int eo = l >> 4;      // edge slot
    const int hh = c >> 1;      // head of this lane's channels
    const float ad8 = adb[(size_t)i * 8 + hh];
    const int beg = row_ptr[i], end = row_ptr[i + 1];

    float acc[16];
    #pragma unroll
    for (int j = 0; j < 16; ++j) acc[j] = 0.f;
    float dsum = 0.f;

    int p = beg;
    for (; p + 7 < end; p += 8) {
        int s0 = es[p + eo], s1 = es[p + 4 + eo];
        float a0 = asb[(size_t)s0 * 8 + hh];
        float a1 = asb[(size_t)s1 * 8 + hh];
        uint4 h0 = *(const uint4*)(h8 + (size_t)s0 * 256 + c * 16);
        uint4 h1 = *(const uint4*)(h8 + (size_t)s1 * 256 + c * 16);
        float w0 = edge_w(a0, ad8);
        float w1 = edge_w(a1, ad8);
        ACC4(h0.x, w0, 0); ACC4(h0.y, w0, 4); ACC4(h0.z, w0, 8); ACC4(h0.w, w0, 12);
        ACC4(h1.x, w1, 0); ACC4(h1.y, w1, 4); ACC4(h1.z, w1, 8); ACC4(h1.w, w1, 12);
        dsum += w0 + w1;
    }
    for (; p < end; p += 4) {
        int pe = p + eo;
        int pc = pe < end ? pe : end - 1;
        int s0 = es[pc];
        float w0 = pe < end ? edge_w(asb[(size_t)s0 * 8 + hh], ad8) : 0.f;
        uint4 h0 = *(const uint4*)(h8 + (size_t)s0 * 256 + c * 16);
        ACC4(h0.x, w0, 0); ACC4(h0.y, w0, 4); ACC4(h0.z, w0, 8); ACC4(h0.w, w0, 12);
        dsum += w0;
    }

    #pragma unroll
    for (int j = 0; j < 16; ++j) {
        acc[j] += __shfl_xor(acc[j], 32);
        acc[j] += __shfl_xor(acc[j], 16);
    }
    dsum += __shfl_xor(dsum, 32);
    dsum += __shfl_xor(dsum, 16);

    float inv = 1.f / (dsum + 1e-16f);
    if (eo == 0) {
        union { short s[16]; bf16x8 v[2]; } zz;
        #pragma unroll
        for (int j = 0; j < 16; ++j) {
            float z = acc[j] * inv + bias[c * 16 + j];
            zz.s[j] = f2bf(z > 0.f ? z : 0.f);
        }
        *(bf16x8*)(z_bf + (size_t)i * HC + c * 16)     = zz.v[0];
        *(bf16x8*)(z_bf + (size_t)i * HC + c * 16 + 8) = zz.v[1];
    }
}

__global__ __launch_bounds__(256) void agg2_kernel(const unsigned char* __restrict__ h8,
    const float* __restrict__ asb, const float* __restrict__ adb,
    const int* __restrict__ row_ptr, const int* __restrict__ es,
    const float* __restrict__ b2, const float* __restrict__ Wp,
    const float* __restrict__ bp, float* __restrict__ out, int N)
{
    const int l  = threadIdx.x & 63;
    const int i  = blockIdx.x * 4 + (threadIdx.x >> 6);
    if (i >= N) return;
    const int c  = l & 15;
    const int eo = l >> 4;
    const int hh = c >> 1;
    const float ad8 = adb[(size_t)i * 8 + hh];
    const int beg = row_ptr[i], end = row_ptr[i + 1];

    float acc[16];
    #pragma unroll
    for (int j = 0; j < 16; ++j) acc[j] = 0.f;
    float dsum = 0.f;

    int p = beg;
    for (; p + 7 < end; p += 8) {
        int s0 = es[p + eo], s1 = es[p + 4 + eo];
        float a0 = asb[(size_t)s0 * 8 + hh];
        float a1 = asb[(size_t)s1 * 8 + hh];
        uint4 h0 = *(const uint4*)(h8 + (size_t)s0 * 256 + c * 16);
        uint4 h1 = *(const uint4*)(h8 + (size_t)s1 * 256 + c * 16);
        float w0 = edge_w(a0, ad8);
        float w1 = edge_w(a1, ad8);
        ACC4(h0.x, w0, 0); ACC4(h0.y, w0, 4); ACC4(h0.z, w0, 8); ACC4(h0.w, w0, 12);
        ACC4(h1.x, w1, 0); ACC4(h1.y, w1, 4); ACC4(h1.z, w1, 8); ACC4(h1.w, w1, 12);
        dsum += w0 + w1;
    }
    for (; p < end; p += 4) {
        int pe = p + eo;
        int pc = pe < end ? pe : end - 1;
        int s0 = es[pc];
        float w0 = pe < end ? edge_w(asb[(size_t)s0 * 8 + hh], ad8) : 0.f;
        uint4 h0 = *(const uint4*)(h8 + (size_t)s0 * 256 + c * 16);
        ACC4(h0.x, w0, 0); ACC4(h0.y, w0, 4); ACC4(h0.z, w0, 8); ACC4(h0.w, w0, 12);
        dsum += w0;
    }

    #pragma unroll
    for (int j = 0; j < 16; ++j) {
        acc[j] += __shfl_xor(acc[j], 32);
        acc[j] += __shfl_xor(acc[j], 16);
    }
    dsum += __shfl_xor(dsum, 32);
    dsum += __shfl_xor(dsum, 16);

    float inv = 1.f / (dsum + 1e-16f);
    const int wb = (c & 1) << 4;     // Wp index base = (16c+j) & 31
    float partial = 0.f;
    #pragma unroll
    for (int j = 0; j < 16; ++j) partial = fmaf(acc[j] * inv, Wp[wb + j], partial);
    if (eo == 0 && c < 2) {
        #pragma unroll
        for (int j = 0; j < 16; ++j) partial += 8.f * b2[c * 16 + j] * Wp[c * 16 + j];
    }
    #pragma unroll
    for (int off = 8; off > 0; off >>= 1) partial += __shfl_xor(partial, off);
    if (l == 0) out[i] = 1.f / (1.f + __expf(-(0.125f * partial + bp[0])));
}

// ---------------------------------------------------------------------------
extern "C" void kernel_launch(void* const* d_in, const int* in_sizes, int n_in,
                              void* d_out, int out_size, void* d_ws, size_t ws_size,
                              hipStream_t stream)
{
    const int*   ei  = (const int*)d_in[0];
    const float* x   = (const float*)d_in[1];
    const float* W1  = (const float*)d_in[2];
    const float* as1 = (const float*)d_in[3];
    const float* ad1 = (const float*)d_in[4];
    const float* b1  = (const float*)d_in[5];
    const float* W2  = (const float*)d_in[6];
    const float* as2 = (const float*)d_in[7];
    const float* ad2 = (const float*)d_in[8];
    const float* b2  = (const float*)d_in[9];
    const float* Wp  = (const float*)d_in[10];
    const float* bp  = (const float*)d_in[11];
    float* out = (float*)d_out;

    const int E = in_sizes[0] / 2;
    const int N = in_sizes[1] / F_IN;
    const int ET = E + N;

    // workspace layout (16B-aligned sections)
    float*         asb = (float*)d_ws;                           // N*8 f32
    float*         adb = asb + (size_t)N * H_HEADS;              // N*8 f32
    unsigned char* h8  = (unsigned char*)(adb + (size_t)N * H_HEADS); // N*256 fp8
    short*         z1b = (short*)(h8 + (size_t)N * HC);          // N*256 bf16
    short*         Wf1 = z1b + (size_t)N * HC;                   // 512*256 bf16
    short*         Wf2 = Wf1 + (size_t)F_IN * HC;                // 256*256 bf16
    int*           es  = (int*)(Wf2 + (size_t)HC * HC);          // (E+N) int (src)
    int* cnt       = es + ET;                                    // N
    int* row_ptr   = cnt + N;                                    // N+1
    int* chunk_sum = row_ptr + N + 1;                            // 64

    const int NCH = (N + 1023) / 1024;
    const int MB  = ((N + 63) / 64) * 2;     // stripes x 2 column halves
    const int NB4 = (N + 3) / 4;

    // ---- CSR build ----
    zero_int<<<(N + 255) / 256, 256, 0, stream>>>(cnt, N);
    hist_kernel<<<(ET + 255) / 256, 256, 0, stream>>>(ei, E, N, cnt);
    scan_sum<<<NCH, 256, 0, stream>>>(cnt, N, chunk_sum);
    scan_local<<<NCH, 256, 0, stream>>>(cnt, N, chunk_sum, NCH, row_ptr);
    scatter_kernel<<<(ET + 255) / 256, 256, 0, stream>>>(ei, E, N, row_ptr, cnt, es);

    // ---- W repack (single launch) ----
    wfrag_kernel<<<(F_IN * HC + HC * HC + 255) / 256, 256, 0, stream>>>(W1, W2, Wf1, Wf2);

    // ---- Layer 1 ----
    gemm_mfma<false><<<MB, 256, 0, stream>>>(x, Wf1, h8, as1, ad1, asb, adb, N, F_IN);
    agg1_kernel<<<NB4, 256, 0, stream>>>(h8, asb, adb, row_ptr, es, b1, z1b, N);

    // ---- Layer 2 ----
    gemm_mfma<true><<<MB, 256, 0, stream>>>(z1b, Wf2, h8, as2, ad2, asb, adb, N, HC);
    agg2_kernel<<<NB4, 256, 0, stream>>>(h8, asb, adb, row_ptr, es, b2, Wp, bp, out, N);
}

// Round 10
// 393.642 us; speedup vs baseline: 1.3710x; 1.0156x over previous
//
#include <hip/hip_runtime.h>
#include <math.h>

#define H_HEADS 8
#define C_DIM   32
#define HC      256
#define F_IN    512
#define NEG_SLOPE 0.2f

typedef __attribute__((ext_vector_type(8))) short    bf16x8;
typedef __attribute__((ext_vector_type(4))) short    s16x4;
typedef __attribute__((ext_vector_type(4))) float    f32x4;
typedef __attribute__((ext_vector_type(2))) float    f32x2;

__device__ __forceinline__ short f2bf(float f) {
    union { float f; unsigned u; } v; v.f = f;
    unsigned r = v.u + 0x7FFF + ((v.u >> 16) & 1);   // RNE
    return (short)(r >> 16);
}

// packed fp32->bf16 (RNE), 8 elems in 4 instructions
__device__ __forceinline__ bf16x8 cvt8(float4 a, float4 b) {
    union { bf16x8 v; unsigned u[4]; } r;
    asm("v_cvt_pk_bf16_f32 %0, %1, %2" : "=v"(r.u[0]) : "v"(a.x), "v"(a.y));
    asm("v_cvt_pk_bf16_f32 %0, %1, %2" : "=v"(r.u[1]) : "v"(a.z), "v"(a.w));
    asm("v_cvt_pk_bf16_f32 %0, %1, %2" : "=v"(r.u[2]) : "v"(b.x), "v"(b.y));
    asm("v_cvt_pk_bf16_f32 %0, %1, %2" : "=v"(r.u[3]) : "v"(b.z), "v"(b.w));
    return r.v;
}

__device__ __forceinline__ void gl2lds16(const short* g, short* l) {
    __builtin_amdgcn_global_load_lds(
        (const __attribute__((address_space(1))) void*)g,
        (__attribute__((address_space(3))) void*)l, 16, 0, 0);
}

// ---------------------------------------------------------------------------
// MFMA GEMM + fused epilogue — N-split (64 rows x 128 cols per block) with
// BK=64: TWO K-sub-steps per barrier round. Phases: 16 -> 8 (L1), 8 -> 4 (L2).
// Each round: stage 16 KB (4 gl2lds/thread), prefetch 2 A sub-steps (more
// MLP/wave), 16 MFMAs. 34 KB LDS -> 4 blocks/CU.
// ---------------------------------------------------------------------------
#define STAGE(ss, buf) do { \
    const short* g_ = Bf + (size_t)(ss) * 8192 + cb * 4096 + w * 512 + lane * 8; \
    short* l_ = &Bs[buf][((ss) & 1) * 4096 + w * 512 + lane * 8]; \
    gl2lds16(g_, l_); \
    gl2lds16(g_ + 2048, l_ + 2048); \
} while (0)

template<bool ABF16>
__global__ __launch_bounds__(256) void gemm_mfma(const void* __restrict__ Aptr,
    const short* __restrict__ Bf, unsigned char* __restrict__ h8,
    const float* __restrict__ a_s, const float* __restrict__ a_d,
    float* __restrict__ alpha_s, float* __restrict__ alpha_d, int M, int K)
{
    __shared__ short Bs[2][8192];            // 2 x 16 KB (BK=64 x 128 cols)
    __shared__ float Als[256], Ald[256];     // 64 rows x 4 heads

    const int tid  = threadIdx.x;
    const int w    = tid >> 6;
    const int lane = tid & 63;
    const int quad = lane >> 4;
    const int ml   = lane & 15;
    const int cb   = blockIdx.x & 1;         // column half (pair shares A rows)
    const int bm   = (blockIdx.x >> 1) * 64;

    const int rowA = bm + w * 16 + ml;
    const int rowL = rowA < M ? rowA : M - 1;
    const size_t aoff = (size_t)rowL * K + quad * 8;
    const float* Ar32 = (const float*)Aptr + aoff;
    const short* Ar16 = (const short*)Aptr + aoff;

    f32x4 acc[8];
    #pragma unroll
    for (int nb = 0; nb < 8; ++nb) acc[nb] = (f32x4){0.f, 0.f, 0.f, 0.f};

    const int nph = K >> 6;

    STAGE(0, 0);
    STAGE(1, 0);

    float4 pf0, pf1, pf2, pf3;
    bf16x8 pb0, pb1;
    if (ABF16) {
        pb0 = *(const bf16x8*)(Ar16);
        pb1 = *(const bf16x8*)(Ar16 + 32);
    } else {
        pf0 = *(const float4*)(Ar32);
        pf1 = *(const float4*)(Ar32 + 4);
        pf2 = *(const float4*)(Ar32 + 32);
        pf3 = *(const float4*)(Ar32 + 36);
    }

    for (int p = 0; p < nph; ++p) {
        __syncthreads();

        if (p + 1 < nph) {
            STAGE(2 * p + 2, (p + 1) & 1);
            STAGE(2 * p + 3, (p + 1) & 1);
        }

        bf16x8 af0, af1;
        if (ABF16) {
            af0 = pb0; af1 = pb1;
            if (p + 1 < nph) {
                pb0 = *(const bf16x8*)(Ar16 + (p + 1) * 64);
                pb1 = *(const bf16x8*)(Ar16 + (p + 1) * 64 + 32);
            }
        } else {
            af0 = cvt8(pf0, pf1);
            af1 = cvt8(pf2, pf3);
            if (p + 1 < nph) {
                pf0 = *(const float4*)(Ar32 + (p + 1) * 64);
                pf1 = *(const float4*)(Ar32 + (p + 1) * 64 + 4);
                pf2 = *(const float4*)(Ar32 + (p + 1) * 64 + 32);
                pf3 = *(const float4*)(Ar32 + (p + 1) * 64 + 36);
            }
        }

        const short* b0 = &Bs[p & 1][lane * 8];
        #pragma unroll
        for (int nb = 0; nb < 8; ++nb) {
            bf16x8 bfr = *(const bf16x8*)(b0 + nb * 512);
            acc[nb] = __builtin_amdgcn_mfma_f32_16x16x32_bf16(af0, bfr, acc[nb], 0, 0, 0);
        }
        const short* b1 = &Bs[p & 1][4096 + lane * 8];
        #pragma unroll
        for (int nb = 0; nb < 8; ++nb) {
            bf16x8 bfr = *(const bf16x8*)(b1 + nb * 512);
            acc[nb] = __builtin_amdgcn_mfma_f32_16x16x32_bf16(af1, bfr, acc[nb], 0, 0, 0);
        }
    }

    // ---- epilogue: fp8 store + fused per-head alpha dots (4 heads/block) ----
    float as_v[8], ad_v[8];
    #pragma unroll
    for (int nb = 0; nb < 8; ++nb) {
        as_v[nb] = a_s[cb * 128 + nb * 16 + ml];
        ad_v[nb] = a_d[cb * 128 + nb * 16 + ml];
    }

    #pragma unroll
    for (int r = 0; r < 4; ++r) {
        const int rl  = w * 16 + quad * 4 + r;
        const int row = bm + rl;

        if (row < M) {
            unsigned char* hrow = h8 + (size_t)row * HC + cb * 128;
            #pragma unroll
            for (int i = 0; i < 4; ++i) {
                int pk = __builtin_amdgcn_cvt_pk_fp8_f32(acc[2 * i][r], acc[2 * i + 1][r], 0, false);
                hrow[(2 * i) * 16 + ml]     = (unsigned char)(pk & 0xFF);
                hrow[(2 * i + 1) * 16 + ml] = (unsigned char)((pk >> 8) & 0xFF);
            }
        }

        float hs[4], hd[4];
        #pragma unroll
        for (int q = 0; q < 4; ++q) {
            hs[q] = acc[2 * q][r] * as_v[2 * q] + acc[2 * q + 1][r] * as_v[2 * q + 1];
            hd[q] = acc[2 * q][r] * ad_v[2 * q] + acc[2 * q + 1][r] * ad_v[2 * q + 1];
        }
        #pragma unroll
        for (int off = 1; off < 16; off <<= 1) {
            #pragma unroll
            for (int q = 0; q < 4; ++q) {
                hs[q] += __shfl_xor(hs[q], off);
                hd[q] += __shfl_xor(hd[q], off);
            }
        }
        if (ml == 0) {
            #pragma unroll
            for (int q = 0; q < 4; ++q) {
                Als[rl * 4 + q] = hs[q];
                Ald[rl * 4 + q] = hd[q];
            }
        }
    }
    __syncthreads();
    {
        int rl = tid >> 2, q = tid & 3;      // 256 = 64 rows x 4 heads
        int row = bm + rl;
        if (row < M) {
            alpha_s[(size_t)row * H_HEADS + cb * 4 + q] = Als[tid];
            alpha_d[(size_t)row * H_HEADS + cb * 4 + q] = Ald[tid];
        }
    }
}

// ---------------------------------------------------------------------------
// CSR build
// ---------------------------------------------------------------------------
__global__ void zero_int(int* __restrict__ p, int n)
{
    int i = blockIdx.x * 256 + threadIdx.x;
    if (i < n) p[i] = 0;
}

__global__ void hist_kernel(const int* __restrict__ ei, int E, int N,
                            int* __restrict__ cnt)
{
    int e = blockIdx.x * 256 + threadIdx.x;
    if (e < E) atomicAdd(&cnt[ei[E + e]], 1);
    else if (e < E + N) atomicAdd(&cnt[e - E], 1);
}

__global__ __launch_bounds__(256) void scan_sum(const int* __restrict__ cnt, int n,
                                                int* __restrict__ chunk_sum)
{
    __shared__ int lds[256];
    int b = blockIdx.x, t = threadIdx.x;
    int base = b * 1024 + t * 4;
    int s = 0;
    #pragma unroll
    for (int j = 0; j < 4; ++j) { int i = base + j; if (i < n) s += cnt[i]; }
    lds[t] = s; __syncthreads();
    for (int off = 128; off > 0; off >>= 1) {
        if (t < off) lds[t] += lds[t + off];
        __syncthreads();
    }
    if (t == 0) chunk_sum[b] = lds[0];
}

// scan_local with inlined chunk-offset reduce (each wave reduces <=64 sums).
__global__ __launch_bounds__(256) void scan_local(const int* __restrict__ cnt, int n,
    const int* __restrict__ chunk_sum, int nch, int* __restrict__ row_ptr)
{
    __shared__ int lds[256];
    int b = blockIdx.x, t = threadIdx.x;
    int lane = t & 63;

    int cs  = (lane < nch) ? chunk_sum[lane] : 0;
    int pre = (lane < b)   ? cs : 0;
    int tot = cs;
    #pragma unroll
    for (int off = 32; off > 0; off >>= 1) {
        pre += __shfl_xor(pre, off);
        tot += __shfl_xor(tot, off);
    }

    int base = b * 1024 + t * 4;
    int v[4]; int s = 0;
    #pragma unroll
    for (int j = 0; j < 4; ++j) { int i = base + j; v[j] = (i < n) ? cnt[i] : 0; s += v[j]; }
    lds[t] = s; __syncthreads();
    for (int off = 1; off < 256; off <<= 1) {
        int u = (t >= off) ? lds[t - off] : 0;
        __syncthreads();
        lds[t] += u;
        __syncthreads();
    }
    int run = lds[t] - s + pre;
    #pragma unroll
    for (int j = 0; j < 4; ++j) {
        int i = base + j;
        if (i < n) row_ptr[i] = run;
        run += v[j];
    }
    if (b == gridDim.x - 1 && t == 0) row_ptr[n] = tot;
}

// Reverse-fill scatter (consumes cnt via atomicSub) FUSED with the W repack:
// the first NW1+NW2 global threads additionally convert one W element to the
// MFMA B-frag layout (independent work, saves one dispatch).
__global__ void scatter_wfrag_kernel(const int* __restrict__ ei, int E, int N,
    const int* __restrict__ row_ptr, int* __restrict__ cnt, int* __restrict__ es,
    const float* __restrict__ W1, const float* __restrict__ W2,
    short* __restrict__ Wf1, short* __restrict__ Wf2)
{
    const int NW1 = F_IN * HC;
    const int NW2 = HC * HC;
    int e = blockIdx.x * 256 + threadIdx.x;

    if (e < NW1 + NW2) {
        const float* W; short* Wf; int t;
        if (e < NW1) { W = W1; Wf = Wf1; t = e; }
        else         { W = W2; Wf = Wf2; t = e - NW1; }
        int j  = t & 7;
        int l  = (t >> 3) & 63;
        int nb = (t >> 9) & 15;
        int s  = t >> 13;
        int k  = s * 32 + (l >> 4) * 8 + j;
        int n  = nb * 16 + (l & 15);
        Wf[t] = f2bf(W[(size_t)k * HC + n]);
    }

    int src, dst;
    if (e < E)          { src = ei[e]; dst = ei[E + e]; }
    else if (e < E + N) { src = dst = e - E; }
    else return;
    int pos = row_ptr[dst] + atomicSub(&cnt[dst], 1) - 1;
    es[pos] = src;
}

// ---------------------------------------------------------------------------
// Aggregation with wcalc FUSED, 4-edges-per-wave layout.
// ---------------------------------------------------------------------------
#define ACC4(word, wgt, base_) do { \
    f32x2 lo_ = __builtin_amdgcn_cvt_pk_f32_fp8((word), false); \
    f32x2 hi_ = __builtin_amdgcn_cvt_pk_f32_fp8((word), true);  \
    acc[(base_) + 0] = fmaf((wgt), lo_[0], acc[(base_) + 0]); \
    acc[(base_) + 1] = fmaf((wgt), lo_[1], acc[(base_) + 1]); \
    acc[(base_) + 2] = fmaf((wgt), hi_[0], acc[(base_) + 2]); \
    acc[(base_) + 3] = fmaf((wgt), hi_[1], acc[(base_) + 3]); \
} while (0)

__device__ __forceinline__ float edge_w(float av, float ad8) {
    float e = av + ad8;
    return __expf(e > 0.f ? e : NEG_SLOPE * e);
}

__global__ __launch_bounds__(256) void agg1_kernel(const unsigned char* __restrict__ h8,
    const float* __restrict__ asb, const float* __restrict__ adb,
    const int* __restrict__ row_ptr, const int* __restrict__ es,
    const float* __restrict__ bias, short* __restrict__ z_bf, int N)
{
    const int l  = threadIdx.x & 63;
    const int i  = blockIdx.x * 4 + (threadIdx.x >> 6);
    if (i >= N) return;
    const int c  = l & 15;      // channels 16c..16c+15
    const int eo = l >> 4;      // edge slot
    const int hh = c >> 1;      // head of this lane's channels
    const float ad8 = adb[(size_t)i * 8 + hh];
    const int beg = row_ptr[i], end = row_ptr[i + 1];

    float acc[16];
    #pragma unroll
    for (int j = 0; j < 16; ++j) acc[j] = 0.f;
    float dsum = 0.f;

    int p = beg;
    for (; p + 7 < end; p += 8) {
        int s0 = es[p + eo], s1 = es[p + 4 + eo];
        float a0 = asb[(size_t)s0 * 8 + hh];
        float a1 = asb[(size_t)s1 * 8 + hh];
        uint4 h0 = *(const uint4*)(h8 + (size_t)s0 * 256 + c * 16);
        uint4 h1 = *(const uint4*)(h8 + (size_t)s1 * 256 + c * 16);
        float w0 = edge_w(a0, ad8);
        float w1 = edge_w(a1, ad8);
        ACC4(h0.x, w0, 0); ACC4(h0.y, w0, 4); ACC4(h0.z, w0, 8); ACC4(h0.w, w0, 12);
        ACC4(h1.x, w1, 0); ACC4(h1.y, w1, 4); ACC4(h1.z, w1, 8); ACC4(h1.w, w1, 12);
        dsum += w0 + w1;
    }
    for (; p < end; p += 4) {
        int pe = p + eo;
        int pc = pe < end ? pe : end - 1;
        int s0 = es[pc];
        float w0 = pe < end ? edge_w(asb[(size_t)s0 * 8 + hh], ad8) : 0.f;
        uint4 h0 = *(const uint4*)(h8 + (size_t)s0 * 256 + c * 16);
        ACC4(h0.x, w0, 0); ACC4(h0.y, w0, 4); ACC4(h0.z, w0, 8); ACC4(h0.w, w0, 12);
        dsum += w0;
    }

    #pragma unroll
    for (int j = 0; j < 16; ++j) {
        acc[j] += __shfl_xor(acc[j], 32);
        acc[j] += __shfl_xor(acc[j], 16);
    }
    dsum += __shfl_xor(dsum, 32);
    dsum += __shfl_xor(dsum, 16);

    float inv = 1.f / (dsum + 1e-16f);
    if (eo == 0) {
        union { short s[16]; bf16x8 v[2]; } zz;
        #pragma unroll
        for (int j = 0; j < 16; ++j) {
            float z = acc[j] * inv + bias[c * 16 + j];
            zz.s[j] = f2bf(z > 0.f ? z : 0.f);
        }
        *(bf16x8*)(z_bf + (size_t)i * HC + c * 16)     = zz.v[0];
        *(bf16x8*)(z_bf + (size_t)i * HC + c * 16 + 8) = zz.v[1];
    }
}

__global__ __launch_bounds__(256) void agg2_kernel(const unsigned char* __restrict__ h8,
    const float* __restrict__ asb, const float* __restrict__ adb,
    const int* __restrict__ row_ptr, const int* __restrict__ es,
    const float* __restrict__ b2, const float* __restrict__ Wp,
    const float* __restrict__ bp, float* __restrict__ out, int N)
{
    const int l  = threadIdx.x & 63;
    const int i  = blockIdx.x * 4 + (threadIdx.x >> 6);
    if (i >= N) return;
    const int c  = l & 15;
    const int eo = l >> 4;
    const int hh = c >> 1;
    const float ad8 = adb[(size_t)i * 8 + hh];
    const int beg = row_ptr[i], end = row_ptr[i + 1];

    float acc[16];
    #pragma unroll
    for (int j = 0; j < 16; ++j) acc[j] = 0.f;
    float dsum = 0.f;

    int p = beg;
    for (; p + 7 < end; p += 8) {
        int s0 = es[p + eo], s1 = es[p + 4 + eo];
        float a0 = asb[(size_t)s0 * 8 + hh];
        float a1 = asb[(size_t)s1 * 8 + hh];
        uint4 h0 = *(const uint4*)(h8 + (size_t)s0 * 256 + c * 16);
        uint4 h1 = *(const uint4*)(h8 + (size_t)s1 * 256 + c * 16);
        float w0 = edge_w(a0, ad8);
        float w1 = edge_w(a1, ad8);
        ACC4(h0.x, w0, 0); ACC4(h0.y, w0, 4); ACC4(h0.z, w0, 8); ACC4(h0.w, w0, 12);
        ACC4(h1.x, w1, 0); ACC4(h1.y, w1, 4); ACC4(h1.z, w1, 8); ACC4(h1.w, w1, 12);
        dsum += w0 + w1;
    }
    for (; p < end; p += 4) {
        int pe = p + eo;
        int pc = pe < end ? pe : end - 1;
        int s0 = es[pc];
        float w0 = pe < end ? edge_w(asb[(size_t)s0 * 8 + hh], ad8) : 0.f;
        uint4 h0 = *(const uint4*)(h8 + (size_t)s0 * 256 + c * 16);
        ACC4(h0.x, w0, 0); ACC4(h0.y, w0, 4); ACC4(h0.z, w0, 8); ACC4(h0.w, w0, 12);
        dsum += w0;
    }

    #pragma unroll
    for (int j = 0; j < 16; ++j) {
        acc[j] += __shfl_xor(acc[j], 32);
        acc[j] += __shfl_xor(acc[j], 16);
    }
    dsum += __shfl_xor(dsum, 32);
    dsum += __shfl_xor(dsum, 16);

    float inv = 1.f / (dsum + 1e-16f);
    const int wb = (c & 1) << 4;     // Wp index base = (16c+j) & 31
    float partial = 0.f;
    #pragma unroll
    for (int j = 0; j < 16; ++j) partial = fmaf(acc[j] * inv, Wp[wb + j], partial);
    if (eo == 0 && c < 2) {
        #pragma unroll
        for (int j = 0; j < 16; ++j) partial += 8.f * b2[c * 16 + j] * Wp[c * 16 + j];
    }
    #pragma unroll
    for (int off = 8; off > 0; off >>= 1) partial += __shfl_xor(partial, off);
    if (l == 0) out[i] = 1.f / (1.f + __expf(-(0.125f * partial + bp[0])));
}

// ---------------------------------------------------------------------------
extern "C" void kernel_launch(void* const* d_in, const int* in_sizes, int n_in,
                              void* d_out, int out_size, void* d_ws, size_t ws_size,
                              hipStream_t stream)
{
    const int*   ei  = (const int*)d_in[0];
    const float* x   = (const float*)d_in[1];
    const float* W1  = (const float*)d_in[2];
    const float* as1 = (const float*)d_in[3];
    const float* ad1 = (const float*)d_in[4];
    const float* b1  = (const float*)d_in[5];
    const float* W2  = (const float*)d_in[6];
    const float* as2 = (const float*)d_in[7];
    const float* ad2 = (const float*)d_in[8];
    const float* b2  = (const float*)d_in[9];
    const float* Wp  = (const float*)d_in[10];
    const float* bp  = (const float*)d_in[11];
    float* out = (float*)d_out;

    const int E = in_sizes[0] / 2;
    const int N = in_sizes[1] / F_IN;
    const int ET = E + N;

    // workspace layout (16B-aligned sections)
    float*         asb = (float*)d_ws;                           // N*8 f32
    float*         adb = asb + (size_t)N * H_HEADS;              // N*8 f32
    unsigned char* h8  = (unsigned char*)(adb + (size_t)N * H_HEADS); // N*256 fp8
    short*         z1b = (short*)(h8 + (size_t)N * HC);          // N*256 bf16
    short*         Wf1 = z1b + (size_t)N * HC;                   // 512*256 bf16
    short*         Wf2 = Wf1 + (size_t)F_IN * HC;                // 256*256 bf16
    int*           es  = (int*)(Wf2 + (size_t)HC * HC);          // (E+N) int (src)
    int* cnt       = es + ET;                                    // N
    int* row_ptr   = cnt + N;                                    // N+1
    int* chunk_sum = row_ptr + N + 1;                            // 64

    const int NCH = (N + 1023) / 1024;
    const int MB  = ((N + 63) / 64) * 2;     // stripes x 2 column halves
    const int NB4 = (N + 3) / 4;

    // ---- CSR build ----
    zero_int<<<(N + 255) / 256, 256, 0, stream>>>(cnt, N);
    hist_kernel<<<(ET + 255) / 256, 256, 0, stream>>>(ei, E, N, cnt);
    scan_sum<<<NCH, 256, 0, stream>>>(cnt, N, chunk_sum);
    scan_local<<<NCH, 256, 0, stream>>>(cnt, N, chunk_sum, NCH, row_ptr);
    scatter_wfrag_kernel<<<(ET + 255) / 256, 256, 0, stream>>>(ei, E, N, row_ptr, cnt, es,
                                                               W1, W2, Wf1, Wf2);

    // ---- Layer 1 ----
    gemm_mfma<false><<<MB, 256, 0, stream>>>(x, Wf1, h8, as1, ad1, asb, adb, N, F_IN);
    agg1_kernel<<<NB4, 256, 0, stream>>>(h8, asb, adb, row_ptr, es, b1, z1b, N);

    // ---- Layer 2 ----
    gemm_mfma<true><<<MB, 256, 0, stream>>>(z1b, Wf2, h8, as2, ad2, asb, adb, N, HC);
    agg2_kernel<<<NB4, 256, 0, stream>>>(h8, asb, adb, row_ptr, es, b2, Wp, bp, out, N);
}